// Round 6
// baseline (441.394 us; speedup 1.0000x reference)
//
#include <hip/hip_runtime.h>

typedef unsigned short u16;
typedef __bf16 bf16x8 __attribute__((ext_vector_type(8)));
typedef float f32x4 __attribute__((ext_vector_type(4)));
typedef float f32x2 __attribute__((ext_vector_type(2)));
typedef u16 u16x4 __attribute__((ext_vector_type(4)));
typedef u16 u16x8 __attribute__((ext_vector_type(8)));

// Problem constants
#define SEQ   4096
#define DM    1024
#define DI    2048
#define NTOK  8192      // BATCH * SEQ
#define NXP   68        // DT_RANK + 2*D_STATE
#define DTR   64        // DT_RANK
#define NCH   4096      // BATCH * DI channels for scan
#define CHUNK 32
#define NCHK  128       // SEQ / CHUNK

__device__ __forceinline__ float bf2f(u16 v) {
  union { unsigned u; float f; } x; x.u = ((unsigned)v) << 16; return x.f;
}
__device__ __forceinline__ u16 f2bf(float f) {
  unsigned u = __float_as_uint(f);
  return (u16)((u + 0x7FFFu + ((u >> 16) & 1u)) >> 16);   // RNE
}

// async global->LDS DMA, 16B/lane; LDS dest = wave-uniform base + lane*16
__device__ __forceinline__ void g2l16(const u16* g, u16* l) {
  __builtin_amdgcn_global_load_lds(
      (const __attribute__((address_space(1))) unsigned int*)g,
      (__attribute__((address_space(3))) unsigned int*)l, 16, 0, 0);
}

#define SBAR0() __builtin_amdgcn_sched_barrier(0)

// ---------------------------------------------------------------------------
// Input dtype detection (f32 inputs -> low u16 has huge bf16 exponents)
// ---------------------------------------------------------------------------
__global__ __launch_bounds__(256)
void detect_kernel(const u16* __restrict__ x, int* __restrict__ flag)
{
  __shared__ int tot;
  if (threadIdx.x == 0) tot = 0;
  __syncthreads();
  int cnt = 0;
  for (int i = threadIdx.x; i < 4096; i += 256) {
    const int e = (x[2 * i] >> 7) & 0xFF;
    if (e > 167) cnt++;
  }
  atomicAdd(&tot, cnt);
  __syncthreads();
  if (threadIdx.x == 0) flag[0] = (tot >= 8) ? 1 : 0;
}

// ---------------------------------------------------------------------------
// ONE conversion launch. Blocks < NBB: 6 big weights, 8 elems/thread (no-op
// when inputs are bf16). Blocks >= NBB: 11 small vectors incl. conv_w
// transpose to [4][DI] (always runs).
// ---------------------------------------------------------------------------
#define NW0 4194304   // w_in
#define NW1  139264   // w_xproj
#define NW2  131072   // w_dt
#define NW3 2097152   // w_out
#define NW4 1048576   // ffn_w1
#define NW5 1048576   // ffn_w2
#define NBB 4228      // ceil((sum NW)/8/256)
__global__ __launch_bounds__(256)
void convert_all(const float* __restrict__ s0, const float* __restrict__ s1,
                 const float* __restrict__ s2, const float* __restrict__ s3,
                 const float* __restrict__ s4, const float* __restrict__ s5,
                 u16* __restrict__ d0, u16* __restrict__ d1, u16* __restrict__ d2,
                 u16* __restrict__ d3, u16* __restrict__ d4, u16* __restrict__ d5,
                 const void* t0, const void* t1, const void* t2, const void* t3,
                 const void* t4, const void* t5, const void* t6, const void* t7,
                 const void* t8, const void* t9, const void* t10,
                 u16* __restrict__ dsm, const int* __restrict__ flag)
{
  if (blockIdx.x >= NBB) {
    const int i = (blockIdx.x - NBB) * 256 + threadIdx.x;
    if (i >= 24576) return;
    const void* src; int off; int dsti = i;
    if      (i < 8192)  { src = t0;  off = i;
                          dsti = (off & 3) * DI + (off >> 2); }  // conv_w -> [j][d]
    else if (i < 10240) { src = t1;  off = i - 8192; }   // conv_b
    else if (i < 12288) { src = t2;  off = i - 10240; }  // b_dt
    else if (i < 16384) { src = t3;  off = i - 12288; }  // a_log
    else if (i < 18432) { src = t4;  off = i - 16384; }  // d_skip
    else if (i < 19456) { src = t5;  off = i - 18432; }  // ln1_g
    else if (i < 20480) { src = t6;  off = i - 19456; }  // ln1_b
    else if (i < 21504) { src = t7;  off = i - 20480; }  // ln2_g
    else if (i < 22528) { src = t8;  off = i - 21504; }  // ln2_b
    else if (i < 23552) { src = t9;  off = i - 22528; }  // ffn_b1
    else                { src = t10; off = i - 23552; }  // ffn_b2
    dsm[dsti] = (*flag) ? f2bf(((const float*)src)[off]) : ((const u16*)src)[off];
    return;
  }
  if (*flag == 0) return;
  long e = ((long)blockIdx.x * 256 + threadIdx.x) * 8;
  const long c1 = NW0, c2 = c1 + NW1, c3 = c2 + NW2, c4 = c3 + NW3,
             c5 = c4 + NW4, c6 = c5 + NW5;
  if (e >= c6) return;
  const float* s; u16* d;
  if      (e < c1) { s = s0;          d = d0; }
  else if (e < c2) { s = s1; e -= c1; d = d1; }
  else if (e < c3) { s = s2; e -= c2; d = d2; }
  else if (e < c4) { s = s3; e -= c3; d = d3; }
  else if (e < c5) { s = s4; e -= c4; d = d4; }
  else             { s = s5; e -= c5; d = d5; }
  f32x4 a = *(const f32x4*)(s + e);
  f32x4 b = *(const f32x4*)(s + e + 4);
  u16x8 o;
#pragma unroll
  for (int k = 0; k < 4; ++k) { o[k] = f2bf(a[k]); o[4 + k] = f2bf(b[k]); }
  *(u16x8*)(d + e) = o;
}

// ---------------------------------------------------------------------------
// LayerNorm: 2 rows per block, 8 elems per thread, vectorized loads/stores.
// MODE 0: input dtype per runtime flag (LN1). MODE 1: bf16 always (LN2).
// ---------------------------------------------------------------------------
template<int MODE>
__global__ __launch_bounds__(256)
void ln_kernel(const void* __restrict__ xin, const u16* __restrict__ gw,
               const u16* __restrict__ bw, u16* __restrict__ outp,
               const int* __restrict__ flag)
{
  const int tid = threadIdx.x;
  const int sub = tid >> 7;                  // row within block
  const int col0 = (tid & 127) * 8;
  const int row = blockIdx.x * 2 + sub;
  const bool isf32 = (MODE == 0) ? (*flag != 0) : false;
  float v[8];
  if (isf32) {
    const float* xf = (const float*)xin + (size_t)row * DM + col0;
    f32x4 a = *(const f32x4*)xf, b2 = *(const f32x4*)(xf + 4);
#pragma unroll
    for (int k = 0; k < 4; ++k) { v[k] = a[k]; v[4 + k] = b2[k]; }
  } else {
    u16x8 xb = *(const u16x8*)((const u16*)xin + (size_t)row * DM + col0);
#pragma unroll
    for (int k = 0; k < 8; ++k) v[k] = bf2f(xb[k]);
  }
  float s = 0.f, s2 = 0.f;
#pragma unroll
  for (int k = 0; k < 8; ++k) { s += v[k]; s2 += v[k] * v[k]; }
#pragma unroll
  for (int off = 32; off > 0; off >>= 1) {
    s  += __shfl_down(s,  off);
    s2 += __shfl_down(s2, off);
  }
  __shared__ float red[4], red2[4];
  __shared__ f32x2 stat[2];
  const int wv = tid >> 6;
  if ((tid & 63) == 0) { red[wv] = s; red2[wv] = s2; }
  __syncthreads();
  if ((tid & 127) == 0) {
    float ts = red[sub * 2] + red[sub * 2 + 1];
    float t2 = red2[sub * 2] + red2[sub * 2 + 1];
    float mu = ts * (1.f / DM);
    float var = t2 * (1.f / DM) - mu * mu;
    stat[sub] = f32x2{mu, rsqrtf(var + 1e-5f)};
  }
  __syncthreads();
  const float mu = stat[sub][0], rs = stat[sub][1];
  u16x8 gv = *(const u16x8*)(gw + col0), bv = *(const u16x8*)(bw + col0);
  u16x8 o;
#pragma unroll
  for (int k = 0; k < 8; ++k)
    o[k] = f2bf((v[k] - mu) * rs * bf2f(gv[k]) + bf2f(bv[k]));
  *(u16x8*)(outp + (size_t)row * DM + col0) = o;
}

// ---------------------------------------------------------------------------
// 256x256 8-phase GEMM (in_proj). Cross-phase register prefetch: P4
// prefetches af03(kt+1) after the boundary vmcnt (A(kt+1) landed), so P1's
// critical read path is 4 ds_reads (b01) instead of 12. Read profile
// 4/4/8/8; P4's prefetch overlaps its 16 MFMA.
// EPI 6: split store n0<DI -> Cp else Cp2, row stride DI.
// ---------------------------------------------------------------------------
template<int EPI, int LNBX>
__global__ __launch_bounds__(512, 2)
void gemm256_kernel(const u16* __restrict__ A, const u16* __restrict__ Bc,
                    const u16* __restrict__ Braw, int M, int N, int K,
                    const int* __restrict__ dtflag, void* __restrict__ Cp,
                    void* __restrict__ Cp2)
{
  __shared__ __align__(16) u16 sAB[2][2][2][128 * 64];  // [buf][mat][half]
  (void)M;
  const int fl = *dtflag;
  const u16* __restrict__ B = fl ? Bc : Braw;
  const int tid = threadIdx.x;
  const int w = tid >> 6;         // wave 0..7
  const int lane = tid & 63;
  const int b = blockIdx.x;
  const int wg = (b & 7) * (gridDim.x >> 3) + (b >> 3);  // bijective XCD swizzle
  const int bx = wg & ((1 << LNBX) - 1);
  const int by = wg >> LNBX;
  const int m0 = by * 256;
  const int n0 = bx * 256;
  const int wm = w >> 2;          // 0..1 : A half / 128-row slice
  const int wn = w & 3;           // 0..3 : 64-col slice
  const int r = lane & 15;
  const int q = lane >> 4;
  const int r7 = r & 7;
  const int srow = lane >> 3;                          // stage row in 8-row group
  const int schunk = ((lane & 7) ^ (srow & 7)) << 3;   // inverse-swizzled src chunk

  auto stageA = [&](int buf, int half, int kt) {
#pragma unroll
    for (int j = 0; j < 2; ++j) {
      u16* l = &sAB[buf][0][half][(w * 16 + j * 8) * 64];          // wave-uniform
      const u16* g = A + (size_t)(m0 + half * 128 + w * 16 + j * 8 + srow) * K
                       + (kt << 6) + schunk;
      g2l16(g, l);
    }
  };
  auto stageB = [&](int buf, int half, int kt) {
#pragma unroll
    for (int j = 0; j < 2; ++j) {
      u16* l = &sAB[buf][1][half][(w * 16 + j * 8) * 64];
      const u16* g = B + (size_t)(n0 + half * 128 + w * 16 + j * 8 + srow) * K
                       + (kt << 6) + schunk;
      g2l16(g, l);
    }
  };

  f32x4 acc[8][4];
#pragma unroll
  for (int i = 0; i < 8; ++i)
#pragma unroll
    for (int j = 0; j < 4; ++j)
#pragma unroll
      for (int t = 0; t < 4; ++t) acc[i][j][t] = 0.f;

  bf16x8 af03[4][2], af47[4][2], b01[2][2], b23[2][2];

  const int nk = K >> 6;
  stageA(0, 0, 0); stageA(0, 1, 0); stageB(0, 0, 0); stageB(0, 1, 0);
  if (nk > 1) { stageB(1, 0, 1); stageB(1, 1, 1); }
  if (nk > 1) asm volatile("s_waitcnt vmcnt(4)" ::: "memory");
  else        asm volatile("s_waitcnt vmcnt(0)" ::: "memory");
  SBAR0();
  __builtin_amdgcn_s_barrier();
  SBAR0();
  // prologue pre-read: af03 of tile 0 (buf 0 landed above)
  {
    const u16* bA0 = &sAB[0][0][wm][0];
#pragma unroll
    for (int mf = 0; mf < 4; ++mf)
#pragma unroll
      for (int ks = 0; ks < 2; ++ks)
        af03[mf][ks] = *(const bf16x8*)&bA0[(mf * 16 + r) * 64
                          + ((((ks << 2) + q) ^ r7) << 3)];
  }

  for (int kt = 0; kt < nk; ++kt) {
    const int c = kt & 1;
    const u16* bA = &sAB[c][0][wm][0];
    const u16* bB = &sAB[c][1][wn >> 1][0];
    const int rB = (wn & 1) * 64;

    // ---------- Phase 1: read b01 (af03 prefetched); stage A-lo(kt+1) ----------
#pragma unroll
    for (int nf = 0; nf < 2; ++nf)
#pragma unroll
      for (int ks = 0; ks < 2; ++ks)
        b01[nf][ks] = *(const bf16x8*)&bB[(rB + nf * 16 + r) * 64
                          + ((((ks << 2) + q) ^ r7) << 3)];
    if (kt + 1 < nk) stageA(c ^ 1, 0, kt + 1);
    SBAR0(); __builtin_amdgcn_s_barrier();
    asm volatile("s_waitcnt lgkmcnt(0)" ::: "memory"); SBAR0();
    __builtin_amdgcn_s_setprio(1);
#pragma unroll
    for (int mf = 0; mf < 4; ++mf)
#pragma unroll
      for (int nf = 0; nf < 2; ++nf)
#pragma unroll
        for (int ks = 0; ks < 2; ++ks)
          acc[mf][nf] = __builtin_amdgcn_mfma_f32_16x16x32_bf16(
              af03[mf][ks], b01[nf][ks], acc[mf][nf], 0, 0, 0);
    __builtin_amdgcn_s_setprio(0);
    SBAR0(); __builtin_amdgcn_s_barrier(); SBAR0();

    // ---------- Phase 2: read b23; stage A-hi(kt+1) ----------
#pragma unroll
    for (int nf = 0; nf < 2; ++nf)
#pragma unroll
      for (int ks = 0; ks < 2; ++ks)
        b23[nf][ks] = *(const bf16x8*)&bB[(rB + (nf + 2) * 16 + r) * 64
                          + ((((ks << 2) + q) ^ r7) << 3)];
    if (kt + 1 < nk) stageA(c ^ 1, 1, kt + 1);
    SBAR0(); __builtin_amdgcn_s_barrier();
    asm volatile("s_waitcnt lgkmcnt(0)" ::: "memory"); SBAR0();
    __builtin_amdgcn_s_setprio(1);
#pragma unroll
    for (int mf = 0; mf < 4; ++mf)
#pragma unroll
      for (int nf = 0; nf < 2; ++nf)
#pragma unroll
        for (int ks = 0; ks < 2; ++ks)
          acc[mf][nf + 2] = __builtin_amdgcn_mfma_f32_16x16x32_bf16(
              af03[mf][ks], b23[nf][ks], acc[mf][nf + 2], 0, 0, 0);
    __builtin_amdgcn_s_setprio(0);
    SBAR0(); __builtin_amdgcn_s_barrier(); SBAR0();

    // ---------- Phase 3: read af47; stage B-lo(kt+2) ----------
#pragma unroll
    for (int mf = 0; mf < 4; ++mf)
#pragma unroll
      for (int ks = 0; ks < 2; ++ks)
        af47[mf][ks] = *(const bf16x8*)&bA[((mf + 4) * 16 + r) * 64
                          + ((((ks << 2) + q) ^ r7) << 3)];
    if (kt + 2 < nk) stageB(c, 0, kt + 2);
    SBAR0(); __builtin_amdgcn_s_barrier();
    asm volatile("s_waitcnt lgkmcnt(0)" ::: "memory"); SBAR0();
    __builtin_amdgcn_s_setprio(1);
#pragma unroll
    for (int mf = 0; mf < 4; ++mf)
#pragma unroll
      for (int nf = 0; nf < 2; ++nf)
#pragma unroll
        for (int ks = 0; ks < 2; ++ks)
          acc[mf + 4][nf + 2] = __builtin_amdgcn_mfma_f32_16x16x32_bf16(
              af47[mf][ks], b23[nf][ks], acc[mf + 4][nf + 2], 0, 0, 0);
    __builtin_amdgcn_s_setprio(0);
    SBAR0(); __builtin_amdgcn_s_barrier(); SBAR0();

    // ---------- Phase 4: stage B-hi(kt+2); MFMA; vmcnt; prefetch af03' ----------
    if (kt + 2 < nk) stageB(c, 1, kt + 2);
    SBAR0(); __builtin_amdgcn_s_barrier(); SBAR0();
    __builtin_amdgcn_s_setprio(1);
#pragma unroll
    for (int mf = 0; mf < 4; ++mf)
#pragma unroll
      for (int nf = 0; nf < 2; ++nf)
#pragma unroll
        for (int ks = 0; ks < 2; ++ks)
          acc[mf + 4][nf] = __builtin_amdgcn_mfma_f32_16x16x32_bf16(
              af47[mf][ks], b01[nf][ks], acc[mf + 4][nf], 0, 0, 0);
    __builtin_amdgcn_s_setprio(0);
    SBAR0();
    if (kt + 2 < nk) asm volatile("s_waitcnt vmcnt(4)" ::: "memory");
    else             asm volatile("s_waitcnt vmcnt(0)" ::: "memory");
    SBAR0();
    if (kt + 1 < nk) {
      // A(kt+1) landed (vmcnt above leaves only B(kt+2) in flight).
      // A(c^1) not overwritten until P1(kt+2) — reads have 4-phase margin.
      const u16* bAn = &sAB[c ^ 1][0][wm][0];
#pragma unroll
      for (int mf = 0; mf < 4; ++mf)
#pragma unroll
        for (int ks = 0; ks < 2; ++ks)
          af03[mf][ks] = *(const bf16x8*)&bAn[(mf * 16 + r) * 64
                            + ((((ks << 2) + q) ^ r7) << 3)];
    }
    SBAR0();
    __builtin_amdgcn_s_barrier();
    SBAR0();
  }

  // ---- LDS-transpose epilogue ----
  float* ep = (float*)&sAB[0][0][0][0] + w * 4096;
  const int r2 = lane >> 2;
  const int ccol = ((lane & 3) ^ (r2 & 3)) * 16;
  u16* C6 = (n0 < DI) ? (u16*)Cp : (u16*)Cp2;
  const int c6off = (n0 < DI) ? 0 : DI;
#pragma unroll
  for (int mf = 0; mf < 8; ++mf) {
#pragma unroll
    for (int nf = 0; nf < 4; ++nf)
#pragma unroll
      for (int t = 0; t < 4; ++t)
        ep[(q * 4 + t) * 68 + nf * 16 + r] = acc[mf][nf][t];
    f32x4 w0 = *(const f32x4*)&ep[r2 * 68 + ccol + 0];
    f32x4 w1 = *(const f32x4*)&ep[r2 * 68 + ccol + 4];
    f32x4 w2 = *(const f32x4*)&ep[r2 * 68 + ccol + 8];
    f32x4 w3 = *(const f32x4*)&ep[r2 * 68 + ccol + 12];
    u16x8 o0, o1;
#pragma unroll
    for (int k = 0; k < 4; ++k) {
      o0[k] = f2bf(w0[k]); o0[4 + k] = f2bf(w1[k]);
      o1[k] = f2bf(w2[k]); o1[4 + k] = f2bf(w3[k]);
    }
    const int row = m0 + wm * 128 + mf * 16 + r2;
    const int colg = n0 + wn * 64 + ccol;
    const size_t cb = (size_t)row * DI + (colg - c6off);
    *(u16x8*)&C6[cb] = o0;
    *(u16x8*)&C6[cb + 8] = o1;
  }
}

// ---------------------------------------------------------------------------
// Deep-pipeline 128x128 GEMM "gemm_dp": BK=64, 4 waves, 2 blocks/CU, counted
// vmcnt. Cross-phase prefetch: P2 prefetches b01(kt+1) after its vmcnt
// (B(kt+1) landed), so P1 reads only af (8 instead of 12). N=1024 GEMMs only.
// EPI: 3 +x(flag dtype)->bf16 | 4 +bias,relu->bf16 | 5 +bias+addbf16 -> out
// ---------------------------------------------------------------------------
template<int EPI, int LNBX>
__global__ __launch_bounds__(256, 2)
void gemm_dp(const u16* __restrict__ A, const u16* __restrict__ Bc,
             const u16* __restrict__ Braw, int M, int N, int K,
             const u16* __restrict__ bias, const u16* __restrict__ addbf,
             const float* __restrict__ addf, const int* __restrict__ dtflag,
             void* __restrict__ Cp, void* __restrict__ Cp2)
{
  __shared__ __align__(16) u16 sA[2][128 * 64];   // 32 KiB
  __shared__ __align__(16) u16 sB[2][128 * 64];   // 32 KiB
  (void)M;
  const int fl = *dtflag;
  const u16* __restrict__ B = fl ? Bc : Braw;
  const int tid = threadIdx.x;
  const int lane = tid & 63;
  const int w = tid >> 6;                       // 0..3
  const int b = blockIdx.x;
  const int wg = (b & 7) * ((int)gridDim.x >> 3) + (b >> 3);  // XCD swizzle
  const int bx = wg & ((1 << LNBX) - 1);
  const int by = wg >> LNBX;
  const int m0 = by * 128;
  const int n0 = bx * 128;
  const int wm = (w & 1) * 64;
  const int wn = (w >> 1) * 64;
  const int r = lane & 15;
  const int q = lane >> 4;
  const int r7 = lane & 7;
  const int srow = lane >> 3;                          // 0..7
  const int schunk = ((lane & 7) ^ (srow & 7)) << 3;   // inverse-swizzled src

  // stage one 128x64 tile: 4 g2l16/wave, row-group = j*4 + w (8 rows each)
  auto stage = [&](u16* dst, const u16* gbase, int ld) {
#pragma unroll
    for (int j = 0; j < 4; ++j) {
      u16* l = dst + ((j * 4 + w) * 8) * 64;             // wave-uniform base
      const u16* g = gbase + (size_t)((j * 4 + w) * 8 + srow) * ld + schunk;
      g2l16(g, l);
    }
  };
  const u16* gA = A + (size_t)m0 * K;
  const u16* gB = B + (size_t)n0 * K;

  f32x4 acc[4][4];
#pragma unroll
  for (int i = 0; i < 4; ++i)
#pragma unroll
    for (int j = 0; j < 4; ++j)
#pragma unroll
      for (int t = 0; t < 4; ++t) acc[i][j][t] = 0.f;

  bf16x8 af[4][2], b01[2][2], b23[2][2];

  const int nk = K >> 6;
  // prologue: A(0), B(0), A(1); wait A(0)+B(0), leave A(1) in flight
  stage(&sA[0][0], gA, K);
  stage(&sB[0][0], gB, K);
  if (nk > 1) {
    stage(&sA[1][0], gA + 64, K);
    asm volatile("s_waitcnt vmcnt(4)" ::: "memory");
  } else {
    asm volatile("s_waitcnt vmcnt(0)" ::: "memory");
  }
  SBAR0();
  __builtin_amdgcn_s_barrier();
  SBAR0();
  // prologue pre-read: b01 of tile 0
#pragma unroll
  for (int nf = 0; nf < 2; ++nf)
#pragma unroll
    for (int ks = 0; ks < 2; ++ks)
      b01[nf][ks] = *(const bf16x8*)&sB[0][(wn + nf * 16 + r) * 64
                      + ((((ks << 2) + q) ^ r7) << 3)];

  for (int kt = 0; kt < nk; ++kt) {
    const int c = kt & 1;

    // ---------- Phase 1: read af (b01 prefetched); stage B(kt+1) -> c^1 ----------
#pragma unroll
    for (int mf = 0; mf < 4; ++mf)
#pragma unroll
      for (int ks = 0; ks < 2; ++ks)
        af[mf][ks] = *(const bf16x8*)&sA[c][(wm + mf * 16 + r) * 64
                        + ((((ks << 2) + q) ^ r7) << 3)];
    if (kt + 1 < nk) stage(&sB[c ^ 1][0], gB + (size_t)(kt + 1) * 64, K);
    SBAR0();
    __builtin_amdgcn_s_barrier();
    SBAR0();
    __builtin_amdgcn_s_setprio(1);
#pragma unroll
    for (int mf = 0; mf < 4; ++mf)
#pragma unroll
      for (int nf = 0; nf < 2; ++nf)
#pragma unroll
        for (int ks = 0; ks < 2; ++ks)
          acc[mf][nf] = __builtin_amdgcn_mfma_f32_16x16x32_bf16(
              af[mf][ks], b01[nf][ks], acc[mf][nf], 0, 0, 0);
    __builtin_amdgcn_s_setprio(0);
    SBAR0();

    // ---------- Phase 2: read b23; stage A(kt+2) -> c; vmcnt; prefetch b01' ----------
#pragma unroll
    for (int nf = 0; nf < 2; ++nf)
#pragma unroll
      for (int ks = 0; ks < 2; ++ks)
        b23[nf][ks] = *(const bf16x8*)&sB[c][(wn + (nf + 2) * 16 + r) * 64
                        + ((((ks << 2) + q) ^ r7) << 3)];
    if (kt + 2 < nk) stage(&sA[c][0], gA + (size_t)(kt + 2) * 64, K);
    if (kt + 2 < nk) asm volatile("s_waitcnt vmcnt(4)" ::: "memory");
    else             asm volatile("s_waitcnt vmcnt(0)" ::: "memory");
    SBAR0();
    if (kt + 1 < nk) {
      // B(kt+1) landed (vmcnt above leaves only A(kt+2) in flight);
      // sB[c^1] not overwritten until P1(kt+2).
#pragma unroll
      for (int nf = 0; nf < 2; ++nf)
#pragma unroll
        for (int ks = 0; ks < 2; ++ks)
          b01[nf][ks] = *(const bf16x8*)&sB[c ^ 1][(wn + nf * 16 + r) * 64
                          + ((((ks << 2) + q) ^ r7) << 3)];
    }
    SBAR0();
    __builtin_amdgcn_s_barrier();
    SBAR0();
    __builtin_amdgcn_s_setprio(1);
#pragma unroll
    for (int mf = 0; mf < 4; ++mf)
#pragma unroll
      for (int nf = 0; nf < 2; ++nf)
#pragma unroll
        for (int ks = 0; ks < 2; ++ks)
          acc[mf][nf + 2] = __builtin_amdgcn_mfma_f32_16x16x32_bf16(
              af[mf][ks], b23[nf][ks], acc[mf][nf + 2], 0, 0, 0);
    __builtin_amdgcn_s_setprio(0);
    SBAR0();
  }

  // ---- LDS-transpose epilogue (per-wave 64x64 region, stride 68 f32) ----
  __syncthreads();
  float* ep = (w < 2) ? ((float*)&sA[0][0] + w * 2048)
                      : ((float*)&sB[0][0] + (w - 2) * 2048);
  const int r2 = lane >> 2;
  const int ccol = ((lane & 3) ^ (r2 & 3)) * 16;
#pragma unroll
  for (int i = 0; i < 4; ++i) {
#pragma unroll
    for (int j = 0; j < 4; ++j)
#pragma unroll
      for (int t = 0; t < 4; ++t)
        ep[(q * 4 + t) * 68 + j * 16 + r] = acc[i][j][t];
    f32x4 w0 = *(const f32x4*)&ep[r2 * 68 + ccol + 0];
    f32x4 w1 = *(const f32x4*)&ep[r2 * 68 + ccol + 4];
    f32x4 w2 = *(const f32x4*)&ep[r2 * 68 + ccol + 8];
    f32x4 w3 = *(const f32x4*)&ep[r2 * 68 + ccol + 12];
    float vv[16];
#pragma unroll
    for (int k = 0; k < 4; ++k) {
      vv[k] = w0[k]; vv[4 + k] = w1[k]; vv[8 + k] = w2[k]; vv[12 + k] = w3[k];
    }
    const int row = m0 + wm + i * 16 + r2;
    const int colg = n0 + wn + ccol;
    const size_t idx = (size_t)row * N + colg;
    if (EPI == 3) {               // h = x + v -> bf16
      float ax[16];
      if (fl) {
        f32x4 a0 = *(const f32x4*)&addf[idx];
        f32x4 a1 = *(const f32x4*)&addf[idx + 4];
        f32x4 a2 = *(const f32x4*)&addf[idx + 8];
        f32x4 a3 = *(const f32x4*)&addf[idx + 12];
#pragma unroll
        for (int k = 0; k < 4; ++k) {
          ax[k] = a0[k]; ax[4 + k] = a1[k]; ax[8 + k] = a2[k]; ax[12 + k] = a3[k];
        }
      } else {
        u16x8 a0 = *(const u16x8*)&addbf[idx];
        u16x8 a1 = *(const u16x8*)&addbf[idx + 8];
#pragma unroll
        for (int k = 0; k < 8; ++k) { ax[k] = bf2f(a0[k]); ax[8 + k] = bf2f(a1[k]); }
      }
      u16x8 o0, o1;
#pragma unroll
      for (int k = 0; k < 8; ++k) {
        o0[k] = f2bf(vv[k] + ax[k]); o1[k] = f2bf(vv[8 + k] + ax[8 + k]);
      }
      *(u16x8*)&((u16*)Cp)[idx] = o0;
      *(u16x8*)&((u16*)Cp)[idx + 8] = o1;
    } else if (EPI == 4) {               // relu(v + b1) -> bf16
      u16x8 b0 = *(const u16x8*)&bias[colg];
      u16x8 b1 = *(const u16x8*)&bias[colg + 8];
      u16x8 o0, o1;
#pragma unroll
      for (int k = 0; k < 8; ++k) {
        o0[k] = f2bf(fmaxf(vv[k] + bf2f(b0[k]), 0.f));
        o1[k] = f2bf(fmaxf(vv[8 + k] + bf2f(b1[k]), 0.f));
      }
      *(u16x8*)&((u16*)Cp)[idx] = o0;
      *(u16x8*)&((u16*)Cp)[idx + 8] = o1;
    } else {                             // EPI 5: out = h(bf16) + v + b2
      u16x8 b0 = *(const u16x8*)&bias[colg];
      u16x8 b1 = *(const u16x8*)&bias[colg + 8];
      u16x8 a0 = *(const u16x8*)&addbf[idx];
      u16x8 a1 = *(const u16x8*)&addbf[idx + 8];
      float r0[8], r1[8];
#pragma unroll
      for (int k = 0; k < 8; ++k) {
        r0[k] = vv[k] + bf2f(b0[k]) + bf2f(a0[k]);
        r1[k] = vv[8 + k] + bf2f(b1[k]) + bf2f(a1[k]);
      }
      if (fl) {
        f32x4 f0, f1, f2, f3;
#pragma unroll
        for (int k = 0; k < 4; ++k) { f0[k] = r0[k]; f1[k] = r0[4 + k]; f2[k] = r1[k]; f3[k] = r1[4 + k]; }
        *(f32x4*)&((float*)Cp)[idx] = f0;
        *(f32x4*)&((float*)Cp)[idx + 4] = f1;
        *(f32x4*)&((float*)Cp)[idx + 8] = f2;
        *(f32x4*)&((float*)Cp)[idx + 12] = f3;
      } else {
        u16x8 o0, o1;
#pragma unroll
        for (int k = 0; k < 8; ++k) { o0[k] = f2bf(r0[k]); o1[k] = f2bf(r1[k]); }
        *(u16x8*)&((u16*)Cp)[idx] = o0;
        *(u16x8*)&((u16*)Cp)[idx + 8] = o1;
      }
    }
  }
}

// ---------------------------------------------------------------------------
// Single-K-tile GEMM for dt (M=8192, N=2048, K=64). Stage once -> one
// barrier -> 32 MFMA -> softplus epilogue. No pipeline (write-bound op).
// ---------------------------------------------------------------------------
template<int LNBX>
__global__ __launch_bounds__(256, 2)
void gemm_k64(const u16* __restrict__ A, const u16* __restrict__ Bc,
              const u16* __restrict__ Braw, const int* __restrict__ dtflag,
              const u16* __restrict__ bias, u16* __restrict__ Cp)
{
  __shared__ __align__(16) u16 sA[128 * 64];   // 16 KiB
  __shared__ __align__(16) u16 sB[128 * 64];   // 16 KiB
  const int fl = *dtflag;
  const u16* __restrict__ B = fl ? Bc : Braw;
  const int tid = threadIdx.x;
  const int lane = tid & 63;
  const int w = tid >> 6;
  const int b = blockIdx.x;
  const int wg = (b & 7) * ((int)gridDim.x >> 3) + (b >> 3);
  const int bx = wg & ((1 << LNBX) - 1);
  const int by = wg >> LNBX;
  const int m0 = by * 128;
  const int n0 = bx * 128;
  const int wm = (w & 1) * 64;
  const int wn = (w >> 1) * 64;
  const int r = lane & 15;
  const int q = lane >> 4;
  const int r7 = lane & 7;
  const int srow = lane >> 3;
  const int schunk = ((lane & 7) ^ (srow & 7)) << 3;

  auto stage = [&](u16* dst, const u16* gbase) {
#pragma unroll
    for (int j = 0; j < 4; ++j) {
      u16* l = dst + ((j * 4 + w) * 8) * 64;
      const u16* g = gbase + (size_t)((j * 4 + w) * 8 + srow) * 64 + schunk;
      g2l16(g, l);
    }
  };
  stage(&sA[0], A + (size_t)m0 * 64);
  stage(&sB[0], B + (size_t)n0 * 64);
  asm volatile("s_waitcnt vmcnt(0)" ::: "memory");
  SBAR0();
  __builtin_amdgcn_s_barrier();
  SBAR0();

  f32x4 acc[4][4];
#pragma unroll
  for (int i = 0; i < 4; ++i)
#pragma unroll
    for (int j = 0; j < 4; ++j)
#pragma unroll
      for (int t = 0; t < 4; ++t) acc[i][j][t] = 0.f;

  bf16x8 af[4][2], bfv[4][2];
#pragma unroll
  for (int mf = 0; mf < 4; ++mf)
#pragma unroll
    for (int ks = 0; ks < 2; ++ks)
      af[mf][ks] = *(const bf16x8*)&sA[(wm + mf * 16 + r) * 64
                      + ((((ks << 2) + q) ^ r7) << 3)];
#pragma unroll
  for (int nf = 0; nf < 4; ++nf)
#pragma unroll
    for (int ks = 0; ks < 2; ++ks)
      bfv[nf][ks] = *(const bf16x8*)&sB[(wn + nf * 16 + r) * 64
                      + ((((ks << 2) + q) ^ r7) << 3)];
#pragma unroll
  for (int mf = 0; mf < 4; ++mf)
#pragma unroll
    for (int nf = 0; nf < 4; ++nf)
#pragma unroll
      for (int ks = 0; ks < 2; ++ks)
        acc[mf][nf] = __builtin_amdgcn_mfma_f32_16x16x32_bf16(
            af[mf][ks], bfv[nf][ks], acc[mf][nf], 0, 0, 0);

  // ---- LDS-transpose epilogue + softplus ----
  __syncthreads();
  float* ep = (w < 2) ? ((float*)&sA[0] + w * 2048)
                      : ((float*)&sB[0] + (w - 2) * 2048);
  const int r2 = lane >> 2;
  const int ccol = ((lane & 3) ^ (r2 & 3)) * 16;
#pragma unroll
  for (int i = 0; i < 4; ++i) {
#pragma unroll
    for (int j = 0; j < 4; ++j)
#pragma unroll
      for (int t = 0; t < 4; ++t)
        ep[(q * 4 + t) * 68 + j * 16 + r] = acc[i][j][t];
    f32x4 w0 = *(const f32x4*)&ep[r2 * 68 + ccol + 0];
    f32x4 w1 = *(const f32x4*)&ep[r2 * 68 + ccol + 4];
    f32x4 w2 = *(const f32x4*)&ep[r2 * 68 + ccol + 8];
    f32x4 w3 = *(const f32x4*)&ep[r2 * 68 + ccol + 12];
    float vv[16];
#pragma unroll
    for (int k = 0; k < 4; ++k) {
      vv[k] = w0[k]; vv[4 + k] = w1[k]; vv[8 + k] = w2[k]; vv[12 + k] = w3[k];
    }
    const int row = m0 + wm + i * 16 + r2;
    const int colg = n0 + wn + ccol;
    const size_t idx = (size_t)row * DI + colg;
    u16x8 b0 = *(const u16x8*)&bias[colg];
    u16x8 b1 = *(const u16x8*)&bias[colg + 8];
    u16x8 o0, o1;
#pragma unroll
    for (int k = 0; k < 8; ++k) {
      float v0 = vv[k] + bf2f(b0[k]);
      float v1 = vv[8 + k] + bf2f(b1[k]);
      v0 = (v0 > 15.f) ? v0 : __logf(1.f + __expf(v0));
      v1 = (v1 > 15.f) ? v1 : __logf(1.f + __expf(v1));
      o0[k] = f2bf(v0); o1[k] = f2bf(v1);
    }
    *(u16x8*)&Cp[idx] = o0;
    *(u16x8*)&Cp[idx + 8] = o1;
  }
}

// ---------------------------------------------------------------------------
// x_proj split-K: part[z] = u[:, z*256:(z+1)*256] @ w_xproj[:, same]^T
// ---------------------------------------------------------------------------
__global__ __launch_bounds__(256, 2)
void xproj_splitk(const u16* __restrict__ A, const u16* __restrict__ Bc,
                  const u16* __restrict__ Braw, const int* __restrict__ dtflag,
                  float* __restrict__ part)
{
  __shared__ __align__(16) u16 sA[2][128 * 32];
  __shared__ __align__(16) u16 sB[2][128 * 32];
  const int fl = *dtflag;
  const u16* __restrict__ B = fl ? Bc : Braw;
  const int tid = threadIdx.x;
  const int kz = blockIdx.x;           // 0..7
  const int m0 = blockIdx.y * 128;
  const int kbase = kz * 256;
  const int lane = tid & 63;
  const int wv = tid >> 6;
  const int wm = (wv & 1) * 64;
  const int wn = (wv >> 1) * 64;
  const int r = lane & 15;
  const int q = lane >> 4;
  const int rsw = (r >> 1) & 3;
  const int pr = lane >> 2;
  const int kc = (lane & 3) ^ ((pr >> 1) & 3);
  const int pk = kc * 8;

  u16* lA0[2] = { &sA[0][(wv * 2 + 0) * 512], &sA[1][(wv * 2 + 0) * 512] };
  u16* lA1[2] = { &sA[0][(wv * 2 + 1) * 512], &sA[1][(wv * 2 + 1) * 512] };
  u16* lB0[2] = { &sB[0][(wv * 2 + 0) * 512], &sB[1][(wv * 2 + 0) * 512] };
  u16* lB1[2] = { &sB[0][(wv * 2 + 1) * 512], &sB[1][(wv * 2 + 1) * 512] };
  int br0 = wv * 32 + pr;      if (br0 > 67) br0 = 67;   // junk cols unused
  int br1 = wv * 32 + 16 + pr; if (br1 > 67) br1 = 67;
  const u16* gA0 = A + (size_t)(m0 + wv * 32 + pr) * DI + kbase + pk;
  const u16* gA1 = gA0 + (size_t)16 * DI;
  const u16* gB0 = B + (size_t)br0 * DI + kbase + pk;
  const u16* gB1 = B + (size_t)br1 * DI + kbase + pk;

  f32x4 acc[4][4];
#pragma unroll
  for (int i = 0; i < 4; ++i)
#pragma unroll
    for (int j = 0; j < 4; ++j)
#pragma unroll
      for (int t = 0; t < 4; ++t) acc[i][j][t] = 0.f;

  g2l16(gA0, lA0[0]); g2l16(gA1, lA1[0]);
  g2l16(gB0, lB0[0]); g2l16(gB1, lB1[0]);

  for (int kt = 0; kt < 8; ++kt) {
    const int cur = kt & 1;
    __syncthreads();
    bf16x8 af[4], bfr[4];
#pragma unroll
    for (int i = 0; i < 4; ++i)
      af[i] = *reinterpret_cast<const bf16x8*>(
          &sA[cur][(wm + i * 16 + r) * 32 + (q ^ rsw) * 8]);
#pragma unroll
    for (int j = 0; j < 4; ++j)
      bfr[j] = *reinterpret_cast<const bf16x8*>(
          &sB[cur][(wn + j * 16 + r) * 32 + (q ^ rsw) * 8]);
    if (kt + 1 < 8) {
      gA0 += 32; gA1 += 32; gB0 += 32; gB1 += 32;
      g2l16(gA0, lA0[cur ^ 1]); g2l16(gA1, lA1[cur ^ 1]);
      g2l16(gB0, lB0[cur ^ 1]); g2l16(gB1, lB1[cur ^ 1]);
    }
#pragma unroll
    for (int i = 0; i < 4; ++i)
#pragma unroll
      for (int j = 0; j < 4; ++j)
        acc[i][j] = __builtin_amdgcn_mfma_f32_16x16x32_bf16(af[i], bfr[j], acc[i][j], 0, 0, 0);
  }

#pragma unroll
  for (int i = 0; i < 4; ++i)
#pragma unroll
    for (int j = 0; j < 4; ++j)
#pragma unroll
      for (int t = 0; t < 4; ++t) {
        const int row = m0 + wm + i * 16 + q * 4 + t;
        const int col = wn + j * 16 + r;
        if (col < NXP)
          part[((size_t)kz * NTOK + row) * NXP + col] = acc[i][j][t];
      }
}

// Reduce partials: cols 0..63 -> dtraw bf16 [NTOK,64]; 64..67 -> bc f32 [NTOK,4]
__global__ __launch_bounds__(256)
void xreduce_kernel(const float* __restrict__ part, u16* __restrict__ dtraw,
                    float* __restrict__ bc)
{
  const int i = blockIdx.x * 256 + threadIdx.x;
  if (i >= NTOK * NXP) return;
  const int row = i / NXP, col = i - row * NXP;
  float s = 0.f;
#pragma unroll
  for (int z = 0; z < 8; ++z) s += part[(size_t)z * NTOK * NXP + i];
  if (col < DTR) dtraw[(size_t)row * DTR + col] = f2bf(s);
  else           bc[row * 4 + (col - DTR)] = s;
}

// ---------------------------------------------------------------------------
// Depthwise causal conv + bias + SiLU, 16 tokens per block, window kept
// in registers (reads each xp row ~1.2x instead of 4x).
// ---------------------------------------------------------------------------
#define CTT 16
__global__ __launch_bounds__(256)
void conv_silu_tok(const u16* __restrict__ xp, const u16* __restrict__ cwT,
                   const u16* __restrict__ cb, u16* __restrict__ u)
{
  const int tok0 = blockIdx.x * CTT;        // global token of chunk start
  const int t0 = tok0 & (SEQ - 1);          // position within sequence
  const int d0 = threadIdx.x * 8;
  float w[4][8], cbv[8];
#pragma unroll
  for (int j = 0; j < 4; ++j) {
    u16x8 wv = *(const u16x8*)(cwT + j * DI + d0);
#pragma unroll
    for (int k = 0; k < 8; ++k) w[j][k] = bf2f(wv[k]);
  }
  u16x8 cbb = *(const u16x8*)(cb + d0);
#pragma unroll
  for (int k = 0; k < 8; ++k) cbv[k] = bf2f(cbb[k]);
  float xm0[8], xm1[8], xm2[8];             // x[t-3], x[t-2], x[t-1]
#pragma unroll
  for (int k = 0; k < 8; ++k) { xm0[k] = 0.f; xm1[k] = 0.f; xm2[k] = 0.f; }
  if (t0 != 0) {                            // chunk interior: all 3 priors valid
    u16x8 a = *(const u16x8*)(xp + (size_t)(tok0 - 3) * DI + d0);
    u16x8 bb = *(const u16x8*)(xp + (size_t)(tok0 - 2) * DI + d0);
    u16x8 c = *(const u16x8*)(xp + (size_t)(tok0 - 1) * DI + d0);
#pragma unroll
    for (int k = 0; k < 8; ++k) {
      xm0[k] = bf2f(a[k]); xm1[k] = bf2f(bb[k]); xm2[k] = bf2f(c[k]);
    }
  }
#pragma unroll
  for (int i = 0; i < CTT; ++i) {
    u16x8 xv = *(const u16x8*)(xp + (size_t)(tok0 + i) * DI + d0);
    float xc[8];
    u16x8 o;
#pragma unroll
    for (int k = 0; k < 8; ++k) {
      xc[k] = bf2f(xv[k]);
      const float a = cbv[k] + w[0][k] * xm0[k] + w[1][k] * xm1[k]
                    + w[2][k] * xm2[k] + w[3][k] * xc[k];
      const float sg = 1.f / (1.f + __expf(-a));
      o[k] = f2bf(a * sg);
    }
    *(u16x8*)(u + (size_t)(tok0 + i) * DI + d0) = o;
#pragma unroll
    for (int k = 0; k < 8; ++k) { xm0[k] = xm1[k]; xm1[k] = xm2[k]; xm2[k] = xc[k]; }
  }
}

// ---------------------------------------------------------------------------
// Chunked SSM scan (N=2 states), 4 channels per thread, CHUNK=32.
// ---------------------------------------------------------------------------
__global__ __launch_bounds__(256)
void scan_pass1(const u16* __restrict__ dtb, const u16* __restrict__ ub,
                const float* __restrict__ bc, const u16* __restrict__ a_log,
                float* __restrict__ S, float* __restrict__ hf0, float* __restrict__ hf1)
{
  const int g4 = blockIdx.x * 256 + threadIdx.x;   // NCHK*NCH/4
  const int chg = g4 & (NCH / 4 - 1);
  const int c = g4 >> 10;
  const int ch0 = chg * 4;
  const int b = ch0 >> 11;
  const int d0 = ch0 & (DI - 1);
  u16x8 av = *(const u16x8*)(a_log + d0 * 2);
  float A0[4], A1[4];
#pragma unroll
  for (int k = 0; k < 4; ++k) {
    A0[k] = -__expf(bf2f(av[2 * k]));
    A1[k] = -__expf(bf2f(av[2 * k + 1]));
  }
  float h0[4] = {0.f, 0.f, 0.f, 0.f}, h1[4] = {0.f, 0.f, 0.f, 0.f};
  float s[4] = {0.f, 0.f, 0.f, 0.f};
  const int row0 = b * SEQ + c * CHUNK;
  for (int i = 0; i < CHUNK; ++i) {
    const size_t row = row0 + i;
    u16x4 dtv = *(const u16x4*)(dtb + row * DI + d0);
    u16x4 uv  = *(const u16x4*)(ub + row * DI + d0);
    f32x2 Bv = *(const f32x2*)(bc + row * 4);
#pragma unroll
    for (int k = 0; k < 4; ++k) {
      const float dt = bf2f(dtv[k]);
      const float dtu = dt * bf2f(uv[k]);
      h0[k] = __expf(A0[k] * dt) * h0[k] + dtu * Bv[0];
      h1[k] = __expf(A1[k] * dt) * h1[k] + dtu * Bv[1];
      s[k] += dt;
    }
  }
  const size_t g0 = (size_t)c * NCH + ch0;
  *(f32x4*)(S + g0)   = f32x4{s[0], s[1], s[2], s[3]};
  *(f32x4*)(hf0 + g0) = f32x4{h0[0], h0[1], h0[2], h0[3]};
  *(f32x4*)(hf1 + g0) = f32x4{h1[0], h1[1], h1[2], h1[3]};
}

__global__ __launch_bounds__(256)
void scan_pass2(const float* __restrict__ S, const float* __restrict__ hf0,
                const float* __restrict__ hf1, const u16* __restrict__ a_log,
                float* __restrict__ hi0, float* __restrict__ hi1)
{
  const int ch = blockIdx.x * 256 + threadIdx.x;  // NCH
  const int d = ch & (DI - 1);
  const float A0 = -__expf(bf2f(a_log[d * 2 + 0]));
  const float A1 = -__expf(bf2f(a_log[d * 2 + 1]));
  float h0 = 0.f, h1 = 0.f;
  size_t g = ch;
  float sv = S[g], f0 = hf0[g], f1 = hf1[g];
  for (int c = 0; c < NCHK; ++c) {
    float svn = 0.f, f0n = 0.f, f1n = 0.f;
    if (c + 1 < NCHK) {
      const size_t gn = g + NCH;
      svn = S[gn]; f0n = hf0[gn]; f1n = hf1[gn];
    }
    hi0[g] = h0; hi1[g] = h1;
    h0 = __expf(A0 * sv) * h0 + f0;
    h1 = __expf(A1 * sv) * h1 + f1;
    sv = svn; f0 = f0n; f1 = f1n;
    g += NCH;
  }
}

__global__ __launch_bounds__(256)
void scan_pass3(const u16* __restrict__ dtb, const u16* __restrict__ ub,
                const float* __restrict__ bc, const u16* __restrict__ zbuf,
                const u16* __restrict__ a_log, const u16* __restrict__ d_skip,
                const float* __restrict__ hi0, const float* __restrict__ hi1,
                u16* __restrict__ yb)
{
  const int g4 = blockIdx.x * 256 + threadIdx.x;
  const int chg = g4 & (NCH / 4 - 1);
  const int c = g4 >> 10;
  const int ch0 = chg * 4;
  const int b = ch0 >> 11;
  const int d0 = ch0 & (DI - 1);
  u16x8 av = *(const u16x8*)(a_log + d0 * 2);
  u16x4 dkv = *(const u16x4*)(d_skip + d0);
  float A0[4], A1[4], dsk[4];
#pragma unroll
  for (int k = 0; k < 4; ++k) {
    A0[k] = -__expf(bf2f(av[2 * k]));
    A1[k] = -__expf(bf2f(av[2 * k + 1]));
    dsk[k] = bf2f(dkv[k]);
  }
  const size_t g0 = (size_t)c * NCH + ch0;
  f32x4 h0v = *(const f32x4*)(hi0 + g0);
  f32x4 h1v = *(const f32x4*)(hi1 + g0);
  float h0[4], h1[4];
#pragma unroll
  for (int k = 0; k < 4; ++k) { h0[k] = h0v[k]; h1[k] = h1v[k]; }
  const int row0 = b * SEQ + c * CHUNK;
  for (int i = 0; i < CHUNK; ++i) {
    const size_t row = row0 + i;
    u16x4 dtv = *(const u16x4*)(dtb + row * DI + d0);
    u16x4 uv  = *(const u16x4*)(ub + row * DI + d0);
    u16x4 zv  = *(const u16x4*)(zbuf + row * DI + d0);
    f32x4 bcv = *(const f32x4*)(bc + row * 4);
    u16x4 o;
#pragma unroll
    for (int k = 0; k < 4; ++k) {
      const float dt = bf2f(dtv[k]);
      const float uu = bf2f(uv[k]);
      const float dtu = dt * uu;
      h0[k] = __expf(A0[k] * dt) * h0[k] + dtu * bcv[0];
      h1[k] = __expf(A1[k] * dt) * h1[k] + dtu * bcv[1];
      const float y = h0[k] * bcv[2] + h1[k] * bcv[3];
      const float z = bf2f(zv[k]);
      const float sz = z / (1.f + __expf(-z));
      o[k] = f2bf((y + dsk[k] * uu) * sz);
    }
    *(u16x4*)(yb + row * DI + d0) = o;    // in-place over dtb: ok
  }
}

// ---------------------------------------------------------------------------
extern "C" void kernel_launch(void* const* d_in, const int* in_sizes, int n_in,
                              void* d_out, int out_size, void* d_ws, size_t ws_size,
                              hipStream_t stream)
{
  const void* x       = d_in[0];
  const void* w_in    = d_in[1];
  const void* conv_w  = d_in[2];
  const void* conv_b  = d_in[3];
  const void* w_xproj = d_in[4];
  const void* w_dt    = d_in[5];
  const void* b_dt    = d_in[6];
  const void* a_log   = d_in[7];
  const void* d_skip  = d_in[8];
  const void* w_out   = d_in[9];
  const void* ln1_g   = d_in[10];
  const void* ln1_b   = d_in[11];
  const void* ln2_g   = d_in[12];
  const void* ln2_b   = d_in[13];
  const void* ffn_w1  = d_in[14];
  const void* ffn_b1  = d_in[15];
  const void* ffn_w2  = d_in[16];
  const void* ffn_b2  = d_in[17];
  char* ws = (char*)d_ws;

  // ---- workspace layout (high-water ~127 MB) ----
  const size_t o_flag  = 0;
  const size_t o_small = 256;
  const size_t o_cwout = o_small + 65536;
  const size_t o_cff1  = o_cwout + (size_t)DM * DI * 2;
  const size_t o_cff2  = o_cff1  + (size_t)DM * DM * 2;
  const size_t o_cxp   = o_cff2  + (size_t)DM * DM * 2;
  const size_t o_cwdt  = o_cxp   + (size_t)NXP * DI * 2;
  const size_t o_xn    = 9437184;                         // 16 MiB region
  const size_t o_xp    = o_xn + (size_t)NTOK * DM * 2;    // 32 MiB
  const size_t o_z     = o_xp + (size_t)NTOK * DI * 2;    // 32 MiB
  const size_t o_u     = o_z  + (size_t)NTOK * DI * 2;    // 32 MiB
  const size_t o_bc    = o_u  + (size_t)NTOK * DI * 2;    // 128 KiB
  const size_t SCN = (size_t)NCHK * NCH * 4;              // 2 MiB each
  const size_t o_S   = o_xn + 0 * SCN;
  const size_t o_hf0 = o_xn + 1 * SCN;
  const size_t o_hf1 = o_xn + 2 * SCN;
  const size_t o_hi0 = o_xn + 3 * SCN;
  const size_t o_hi1 = o_xn + 4 * SCN;

  int*   flagp   = (int*)(ws + o_flag);
  u16*   csmall  = (u16*)(ws + o_small);
  u16*   c_cwT   = csmall +     0;       // transposed conv weights [4][DI]
  u16*   c_convb = csmall +  8192;
  u16*   c_bdt   = csmall + 10240;
  u16*   c_alog  = csmall + 12288;
  u16*   c_dskip = csmall + 16384;
  u16*   c_ln1g  = csmall + 18432;
  u16*   c_ln1b  = csmall + 19456;
  u16*   c_ln2g  = csmall + 20480;
  u16*   c_ln2b  = csmall + 21504;
  u16*   c_fb1   = csmall + 22528;
  u16*   c_fb2   = csmall + 23552;
  u16*   c_wout  = (u16*)(ws + o_cwout);
  u16*   c_ff1   = (u16*)(ws + o_cff1);
  u16*   c_ff2   = (u16*)(ws + o_cff2);
  u16*   c_xproj = (u16*)(ws + o_cxp);
  u16*   c_wdt   = (u16*)(ws + o_cwdt);
  u16*   c_win   = (u16*)(ws + o_u);     // overlays u (dead until conv)
  u16*   xn      = (u16*)(ws + o_xn);
  u16*   xp      = (u16*)(ws + o_xp);
  u16*   zb      = (u16*)(ws + o_z);
  u16*   u       = (u16*)(ws + o_u);
  float* part    = (float*)(ws + o_xp);  // overlays xp (dead after conv)
  u16*   dtraw   = (u16*)(ws + o_xn);    // overlays xn (dead after in_proj)
  u16*   dtb     = xp;                   // overlays part (dead after reduce)
  u16*   yb      = xp;
  float* bc      = (float*)(ws + o_bc);
  float* S       = (float*)(ws + o_S);
  float* hf0     = (float*)(ws + o_hf0);
  float* hf1     = (float*)(ws + o_hf1);
  float* hi0     = (float*)(ws + o_hi0);
  float* hi1     = (float*)(ws + o_hi1);
  u16*   hb      = (u16*)(ws + o_z);     // h as bf16, overlays z (dead after pass3)
  u16*   hn      = (u16*)(ws + o_xn);    // overlays scan arrays (dead)
  u16*   f1      = (u16*)(ws + o_u);     // overlays u (dead)

  const dim3 blk(256);

  // 0) detect dtype; all param conversion in ONE launch
  detect_kernel<<<1, blk, 0, stream>>>((const u16*)x, flagp);
  convert_all<<<NBB + 96, blk, 0, stream>>>(
      (const float*)w_in, (const float*)w_xproj, (const float*)w_dt,
      (const float*)w_out, (const float*)ffn_w1, (const float*)ffn_w2,
      c_win, c_xproj, c_wdt, c_wout, c_ff1, c_ff2,
      conv_w, conv_b, b_dt, a_log, d_skip,
      ln1_g, ln1_b, ln2_g, ln2_b, ffn_b1, ffn_b2,
      csmall, flagp);

  // 1) LN1(x) -> xn
  ln_kernel<0><<<NTOK / 2, blk, 0, stream>>>(x, c_ln1g, c_ln1b, xn, flagp);
  // 2) fused in_proj: [xp | z] = xn @ w_in^T  (256x256 8-phase + prefetch)
  gemm256_kernel<6, 4><<<512, dim3(512), 0, stream>>>(
      xn, c_win, (const u16*)w_in, NTOK, 2 * DI, DM, flagp, xp, zb);
  // 3) u = silu(conv(xp) + conv_b)   (16 tokens/block, register window)
  conv_silu_tok<<<NTOK / CTT, blk, 0, stream>>>(xp, c_cwT, c_convb, u);
  // 4) x_proj split-K (partials) + reduce -> dtraw (bf16), bc (f32)
  xproj_splitk<<<dim3(8, 64), blk, 0, stream>>>(u, c_xproj, (const u16*)w_xproj,
                                                flagp, part);
  xreduce_kernel<<<(NTOK * NXP + 255) / 256, blk, 0, stream>>>(part, dtraw, bc);
  // 5) dt = softplus(dtraw @ w_dt^T + b_dt)   (single-K-tile kernel)
  gemm_k64<4><<<1024, blk, 0, stream>>>(dtraw, c_wdt, (const u16*)w_dt,
                                        flagp, c_bdt, dtb);
  // 6) chunked scan -> yb = (y + d_skip*u) * silu(z)
  scan_pass1<<<NCHK * NCH / 4 / 256, blk, 0, stream>>>(dtb, u, bc, c_alog, S, hf0, hf1);
  scan_pass2<<<NCH / 256, blk, 0, stream>>>(S, hf0, hf1, c_alog, hi0, hi1);
  scan_pass3<<<NCHK * NCH / 4 / 256, blk, 0, stream>>>(dtb, u, bc, zb, c_alog, c_dskip,
                                                       hi0, hi1, yb);
  // 7) h = bf16(x + yb @ w_out^T)   (dp + prefetch, grid 64*8=512, nk=32)
  gemm_dp<3, 3><<<512, blk, 0, stream>>>(yb, c_wout, (const u16*)w_out,
                                         NTOK, DM, DI,
                                         nullptr, (const u16*)x, (const float*)x,
                                         flagp, hb, nullptr);
  // 8) LN2(h) -> hn   (bf16 input)
  ln_kernel<1><<<NTOK / 2, blk, 0, stream>>>(hb, c_ln2g, c_ln2b, hn, flagp);
  // 9) f1 = relu(hn @ ffn_w1^T + b1)   (dp + prefetch, nk=16)
  gemm_dp<4, 3><<<512, blk, 0, stream>>>(hn, c_ff1, (const u16*)ffn_w1,
                                         NTOK, DM, DM,
                                         c_fb1, nullptr, nullptr, flagp, f1, nullptr);
  // 10) out = h + f1 @ ffn_w2^T + b2   (dp + prefetch, nk=16)
  gemm_dp<5, 3><<<512, blk, 0, stream>>>(f1, c_ff2, (const u16*)ffn_w2,
                                         NTOK, DM, DM,
                                         c_fb2, hb, nullptr, flagp, d_out, nullptr);
}

// Round 7
// 433.300 us; speedup vs baseline: 1.0187x; 1.0187x over previous
//
#include <hip/hip_runtime.h>

typedef unsigned short u16;
typedef __bf16 bf16x8 __attribute__((ext_vector_type(8)));
typedef float f32x4 __attribute__((ext_vector_type(4)));
typedef float f32x2 __attribute__((ext_vector_type(2)));
typedef u16 u16x4 __attribute__((ext_vector_type(4)));
typedef u16 u16x8 __attribute__((ext_vector_type(8)));

// Problem constants
#define SEQ   4096
#define DM    1024
#define DI    2048
#define NTOK  8192      // BATCH * SEQ
#define NXP   68        // DT_RANK + 2*D_STATE
#define DTR   64        // DT_RANK
#define NCH   4096      // BATCH * DI channels for scan
#define CHUNK 32
#define NCHK  128       // SEQ / CHUNK

__device__ __forceinline__ float bf2f(u16 v) {
  union { unsigned u; float f; } x; x.u = ((unsigned)v) << 16; return x.f;
}
__device__ __forceinline__ u16 f2bf(float f) {
  unsigned u = __float_as_uint(f);
  return (u16)((u + 0x7FFFu + ((u >> 16) & 1u)) >> 16);   // RNE
}

// async global->LDS DMA, 16B/lane; LDS dest = wave-uniform base + lane*16
__device__ __forceinline__ void g2l16(const u16* g, u16* l) {
  __builtin_amdgcn_global_load_lds(
      (const __attribute__((address_space(1))) unsigned int*)g,
      (__attribute__((address_space(3))) unsigned int*)l, 16, 0, 0);
}

#define SBAR0() __builtin_amdgcn_sched_barrier(0)

// ---------------------------------------------------------------------------
// Input dtype detection (f32 inputs -> low u16 has huge bf16 exponents)
// ---------------------------------------------------------------------------
__global__ __launch_bounds__(256)
void detect_kernel(const u16* __restrict__ x, int* __restrict__ flag)
{
  __shared__ int tot;
  if (threadIdx.x == 0) tot = 0;
  __syncthreads();
  int cnt = 0;
  for (int i = threadIdx.x; i < 4096; i += 256) {
    const int e = (x[2 * i] >> 7) & 0xFF;
    if (e > 167) cnt++;
  }
  atomicAdd(&tot, cnt);
  __syncthreads();
  if (threadIdx.x == 0) flag[0] = (tot >= 8) ? 1 : 0;
}

// ---------------------------------------------------------------------------
// ONE conversion launch. Blocks < NBB: 6 big weights, 8 elems/thread (no-op
// when inputs are bf16). Blocks >= NBB: 11 small vectors incl. conv_w
// transpose to [4][DI] (always runs).
// ---------------------------------------------------------------------------
#define NW0 4194304   // w_in
#define NW1  139264   // w_xproj
#define NW2  131072   // w_dt
#define NW3 2097152   // w_out
#define NW4 1048576   // ffn_w1
#define NW5 1048576   // ffn_w2
#define NBB 4228      // ceil((sum NW)/8/256)
__global__ __launch_bounds__(256)
void convert_all(const float* __restrict__ s0, const float* __restrict__ s1,
                 const float* __restrict__ s2, const float* __restrict__ s3,
                 const float* __restrict__ s4, const float* __restrict__ s5,
                 u16* __restrict__ d0, u16* __restrict__ d1, u16* __restrict__ d2,
                 u16* __restrict__ d3, u16* __restrict__ d4, u16* __restrict__ d5,
                 const void* t0, const void* t1, const void* t2, const void* t3,
                 const void* t4, const void* t5, const void* t6, const void* t7,
                 const void* t8, const void* t9, const void* t10,
                 u16* __restrict__ dsm, const int* __restrict__ flag)
{
  if (blockIdx.x >= NBB) {
    const int i = (blockIdx.x - NBB) * 256 + threadIdx.x;
    if (i >= 24576) return;
    const void* src; int off; int dsti = i;
    if      (i < 8192)  { src = t0;  off = i;
                          dsti = (off & 3) * DI + (off >> 2); }  // conv_w -> [j][d]
    else if (i < 10240) { src = t1;  off = i - 8192; }   // conv_b
    else if (i < 12288) { src = t2;  off = i - 10240; }  // b_dt
    else if (i < 16384) { src = t3;  off = i - 12288; }  // a_log
    else if (i < 18432) { src = t4;  off = i - 16384; }  // d_skip
    else if (i < 19456) { src = t5;  off = i - 18432; }  // ln1_g
    else if (i < 20480) { src = t6;  off = i - 19456; }  // ln1_b
    else if (i < 21504) { src = t7;  off = i - 20480; }  // ln2_g
    else if (i < 22528) { src = t8;  off = i - 21504; }  // ln2_b
    else if (i < 23552) { src = t9;  off = i - 22528; }  // ffn_b1
    else                { src = t10; off = i - 23552; }  // ffn_b2
    dsm[dsti] = (*flag) ? f2bf(((const float*)src)[off]) : ((const u16*)src)[off];
    return;
  }
  if (*flag == 0) return;
  long e = ((long)blockIdx.x * 256 + threadIdx.x) * 8;
  const long c1 = NW0, c2 = c1 + NW1, c3 = c2 + NW2, c4 = c3 + NW3,
             c5 = c4 + NW4, c6 = c5 + NW5;
  if (e >= c6) return;
  const float* s; u16* d;
  if      (e < c1) { s = s0;          d = d0; }
  else if (e < c2) { s = s1; e -= c1; d = d1; }
  else if (e < c3) { s = s2; e -= c2; d = d2; }
  else if (e < c4) { s = s3; e -= c3; d = d3; }
  else if (e < c5) { s = s4; e -= c4; d = d4; }
  else             { s = s5; e -= c5; d = d5; }
  f32x4 a = *(const f32x4*)(s + e);
  f32x4 b = *(const f32x4*)(s + e + 4);
  u16x8 o;
#pragma unroll
  for (int k = 0; k < 4; ++k) { o[k] = f2bf(a[k]); o[4 + k] = f2bf(b[k]); }
  *(u16x8*)(d + e) = o;
}

// ---------------------------------------------------------------------------
// LayerNorm: 2 rows per block, 8 elems per thread, vectorized loads/stores.
// MODE 0: input dtype per runtime flag (LN1). MODE 1: bf16 always (LN2).
// ---------------------------------------------------------------------------
template<int MODE>
__global__ __launch_bounds__(256)
void ln_kernel(const void* __restrict__ xin, const u16* __restrict__ gw,
               const u16* __restrict__ bw, u16* __restrict__ outp,
               const int* __restrict__ flag)
{
  const int tid = threadIdx.x;
  const int sub = tid >> 7;                  // row within block
  const int col0 = (tid & 127) * 8;
  const int row = blockIdx.x * 2 + sub;
  const bool isf32 = (MODE == 0) ? (*flag != 0) : false;
  float v[8];
  if (isf32) {
    const float* xf = (const float*)xin + (size_t)row * DM + col0;
    f32x4 a = *(const f32x4*)xf, b2 = *(const f32x4*)(xf + 4);
#pragma unroll
    for (int k = 0; k < 4; ++k) { v[k] = a[k]; v[4 + k] = b2[k]; }
  } else {
    u16x8 xb = *(const u16x8*)((const u16*)xin + (size_t)row * DM + col0);
#pragma unroll
    for (int k = 0; k < 8; ++k) v[k] = bf2f(xb[k]);
  }
  float s = 0.f, s2 = 0.f;
#pragma unroll
  for (int k = 0; k < 8; ++k) { s += v[k]; s2 += v[k] * v[k]; }
#pragma unroll
  for (int off = 32; off > 0; off >>= 1) {
    s  += __shfl_down(s,  off);
    s2 += __shfl_down(s2, off);
  }
  __shared__ float red[4], red2[4];
  __shared__ f32x2 stat[2];
  const int wv = tid >> 6;
  if ((tid & 63) == 0) { red[wv] = s; red2[wv] = s2; }
  __syncthreads();
  if ((tid & 127) == 0) {
    float ts = red[sub * 2] + red[sub * 2 + 1];
    float t2 = red2[sub * 2] + red2[sub * 2 + 1];
    float mu = ts * (1.f / DM);
    float var = t2 * (1.f / DM) - mu * mu;
    stat[sub] = f32x2{mu, rsqrtf(var + 1e-5f)};
  }
  __syncthreads();
  const float mu = stat[sub][0], rs = stat[sub][1];
  u16x8 gv = *(const u16x8*)(gw + col0), bv = *(const u16x8*)(bw + col0);
  u16x8 o;
#pragma unroll
  for (int k = 0; k < 8; ++k)
    o[k] = f2bf((v[k] - mu) * rs * bf2f(gv[k]) + bf2f(bv[k]));
  *(u16x8*)(outp + (size_t)row * DM + col0) = o;
}

// ---------------------------------------------------------------------------
// 256x256 2-phase GEMM (in_proj). R6 falsified "read latency" theory; the
// residual is per-phase overhead (barrier skew / phase-entry serialization
// with 8 lockstep waves). So: 2 phases per K-tile, 2 barriers (was 4 phases,
// 8 barriers). Per K-tile: P1 {read af03+b01+b23 (16), stage A(kt+1),
// lgkm, 32 MFMA}; P2 {read af47 (8), BARRIER (B-WAR), stage B(kt+2), lgkm,
// 32 MFMA, vmcnt(4), BARRIER}. vmcnt(4): outstanding = B(kt+1)@P2(kt-1):4 +
// A(kt+1)@P1(kt):4 + B(kt+2)@P2(kt):4 = 12; wait oldest 8 = A/B(kt+1) landed.
// All cross-wave visibility via barrier AFTER each wave's own vmcnt.
// EPI 6: split store n0<DI -> Cp else Cp2, row stride DI.
// ---------------------------------------------------------------------------
template<int EPI, int LNBX>
__global__ __launch_bounds__(512, 2)
void gemm256_kernel(const u16* __restrict__ A, const u16* __restrict__ Bc,
                    const u16* __restrict__ Braw, int M, int N, int K,
                    const int* __restrict__ dtflag, void* __restrict__ Cp,
                    void* __restrict__ Cp2)
{
  __shared__ __align__(16) u16 sAB[2][2][2][128 * 64];  // [buf][mat][half]
  (void)M;
  const int fl = *dtflag;
  const u16* __restrict__ B = fl ? Bc : Braw;
  const int tid = threadIdx.x;
  const int w = tid >> 6;         // wave 0..7
  const int lane = tid & 63;
  const int b = blockIdx.x;
  const int wg = (b & 7) * (gridDim.x >> 3) + (b >> 3);  // bijective XCD swizzle
  const int bx = wg & ((1 << LNBX) - 1);
  const int by = wg >> LNBX;
  const int m0 = by * 256;
  const int n0 = bx * 256;
  const int wm = w >> 2;          // 0..1 : A half / 128-row slice
  const int wn = w & 3;           // 0..3 : 64-col slice
  const int r = lane & 15;
  const int q = lane >> 4;
  const int r7 = r & 7;
  const int srow = lane >> 3;                          // stage row in 8-row group
  const int schunk = ((lane & 7) ^ (srow & 7)) << 3;   // inverse-swizzled src chunk

  auto stageA = [&](int buf, int half, int kt) {
#pragma unroll
    for (int j = 0; j < 2; ++j) {
      u16* l = &sAB[buf][0][half][(w * 16 + j * 8) * 64];          // wave-uniform
      const u16* g = A + (size_t)(m0 + half * 128 + w * 16 + j * 8 + srow) * K
                       + (kt << 6) + schunk;
      g2l16(g, l);
    }
  };
  auto stageB = [&](int buf, int half, int kt) {
#pragma unroll
    for (int j = 0; j < 2; ++j) {
      u16* l = &sAB[buf][1][half][(w * 16 + j * 8) * 64];
      const u16* g = B + (size_t)(n0 + half * 128 + w * 16 + j * 8 + srow) * K
                       + (kt << 6) + schunk;
      g2l16(g, l);
    }
  };

  f32x4 acc[8][4];
#pragma unroll
  for (int i = 0; i < 8; ++i)
#pragma unroll
    for (int j = 0; j < 4; ++j)
#pragma unroll
      for (int t = 0; t < 4; ++t) acc[i][j][t] = 0.f;

  const int nk = K >> 6;
  // prologue: A(0) both halves, B(0) both halves, B(1) both halves.
  // vmcnt(4): oldest 8 (= A(0),B(0)) landed; B(1) stays in flight.
  stageA(0, 0, 0); stageA(0, 1, 0); stageB(0, 0, 0); stageB(0, 1, 0);
  if (nk > 1) { stageB(1, 0, 1); stageB(1, 1, 1); }
  if (nk > 1) asm volatile("s_waitcnt vmcnt(4)" ::: "memory");
  else        asm volatile("s_waitcnt vmcnt(0)" ::: "memory");
  SBAR0();
  __builtin_amdgcn_s_barrier();
  SBAR0();

  for (int kt = 0; kt < nk; ++kt) {
    const int c = kt & 1;
    const u16* bA = &sAB[c][0][wm][0];
    const u16* bB = &sAB[c][1][wn >> 1][0];
    const int rB = (wn & 1) * 64;
    bf16x8 af03[4][2], af47[4][2], b01[2][2], b23[2][2];

    // ---------- Phase 1: read af03 + b01 + b23; stage A(kt+1) -> c^1 ----------
    // Reads from buf c guaranteed by previous K-tile's end barrier (after
    // each wave's vmcnt). stage A->c^1 WAR-safe: c^1's A reads finished
    // before P2(kt-1)'s MFMA, barrier-separated.
#pragma unroll
    for (int mf = 0; mf < 4; ++mf)
#pragma unroll
      for (int ks = 0; ks < 2; ++ks)
        af03[mf][ks] = *(const bf16x8*)&bA[(mf * 16 + r) * 64
                          + ((((ks << 2) + q) ^ r7) << 3)];
#pragma unroll
    for (int nf = 0; nf < 2; ++nf)
#pragma unroll
      for (int ks = 0; ks < 2; ++ks) {
        b01[nf][ks] = *(const bf16x8*)&bB[(rB + nf * 16 + r) * 64
                          + ((((ks << 2) + q) ^ r7) << 3)];
        b23[nf][ks] = *(const bf16x8*)&bB[(rB + (nf + 2) * 16 + r) * 64
                          + ((((ks << 2) + q) ^ r7) << 3)];
      }
    if (kt + 1 < nk) { stageA(c ^ 1, 0, kt + 1); stageA(c ^ 1, 1, kt + 1); }
    asm volatile("s_waitcnt lgkmcnt(0)" ::: "memory"); SBAR0();
    __builtin_amdgcn_s_setprio(1);
#pragma unroll
    for (int mf = 0; mf < 4; ++mf)
#pragma unroll
      for (int nf = 0; nf < 2; ++nf)
#pragma unroll
        for (int ks = 0; ks < 2; ++ks) {
          acc[mf][nf] = __builtin_amdgcn_mfma_f32_16x16x32_bf16(
              af03[mf][ks], b01[nf][ks], acc[mf][nf], 0, 0, 0);
          acc[mf][nf + 2] = __builtin_amdgcn_mfma_f32_16x16x32_bf16(
              af03[mf][ks], b23[nf][ks], acc[mf][nf + 2], 0, 0, 0);
        }
    __builtin_amdgcn_s_setprio(0);
    SBAR0();

    // ---------- Phase 2: read af47 (pre-barrier, mat0: no hazard);
    //            barrier (B(c) WAR gate); stage B(kt+2) -> c; MFMA ----------
#pragma unroll
    for (int mf = 0; mf < 4; ++mf)
#pragma unroll
      for (int ks = 0; ks < 2; ++ks)
        af47[mf][ks] = *(const bf16x8*)&bA[((mf + 4) * 16 + r) * 64
                          + ((((ks << 2) + q) ^ r7) << 3)];
    SBAR0();
    __builtin_amdgcn_s_barrier();   // all waves' b01/b23 reads complete
    SBAR0();
    if (kt + 2 < nk) { stageB(c, 0, kt + 2); stageB(c, 1, kt + 2); }
    asm volatile("s_waitcnt lgkmcnt(0)" ::: "memory"); SBAR0();
    __builtin_amdgcn_s_setprio(1);
#pragma unroll
    for (int mf = 0; mf < 4; ++mf)
#pragma unroll
      for (int nf = 0; nf < 2; ++nf)
#pragma unroll
        for (int ks = 0; ks < 2; ++ks) {
          acc[mf + 4][nf] = __builtin_amdgcn_mfma_f32_16x16x32_bf16(
              af47[mf][ks], b01[nf][ks], acc[mf + 4][nf], 0, 0, 0);
          acc[mf + 4][nf + 2] = __builtin_amdgcn_mfma_f32_16x16x32_bf16(
              af47[mf][ks], b23[nf][ks], acc[mf + 4][nf + 2], 0, 0, 0);
        }
    __builtin_amdgcn_s_setprio(0);
    SBAR0();
    if (kt + 2 < nk) asm volatile("s_waitcnt vmcnt(4)" ::: "memory");
    else             asm volatile("s_waitcnt vmcnt(0)" ::: "memory");
    SBAR0();
    __builtin_amdgcn_s_barrier();   // cross-wave: A(kt+1)+B(kt+1) visible
    SBAR0();
  }

  // ---- LDS-transpose epilogue (loop ended with full barrier + drain) ----
  float* ep = (float*)&sAB[0][0][0][0] + w * 4096;
  const int r2 = lane >> 2;
  const int ccol = ((lane & 3) ^ (r2 & 3)) * 16;
  u16* C6 = (n0 < DI) ? (u16*)Cp : (u16*)Cp2;
  const int c6off = (n0 < DI) ? 0 : DI;
#pragma unroll
  for (int mf = 0; mf < 8; ++mf) {
#pragma unroll
    for (int nf = 0; nf < 4; ++nf)
#pragma unroll
      for (int t = 0; t < 4; ++t)
        ep[(q * 4 + t) * 68 + nf * 16 + r] = acc[mf][nf][t];
    f32x4 w0 = *(const f32x4*)&ep[r2 * 68 + ccol + 0];
    f32x4 w1 = *(const f32x4*)&ep[r2 * 68 + ccol + 4];
    f32x4 w2 = *(const f32x4*)&ep[r2 * 68 + ccol + 8];
    f32x4 w3 = *(const f32x4*)&ep[r2 * 68 + ccol + 12];
    u16x8 o0, o1;
#pragma unroll
    for (int k = 0; k < 4; ++k) {
      o0[k] = f2bf(w0[k]); o0[4 + k] = f2bf(w1[k]);
      o1[k] = f2bf(w2[k]); o1[4 + k] = f2bf(w3[k]);
    }
    const int row = m0 + wm * 128 + mf * 16 + r2;
    const int colg = n0 + wn * 64 + ccol;
    const size_t cb = (size_t)row * DI + (colg - c6off);
    *(u16x8*)&C6[cb] = o0;
    *(u16x8*)&C6[cb + 8] = o1;
  }
}

// ---------------------------------------------------------------------------
// Deep-pipeline 128x128 GEMM "gemm_dp" (R4-measured version, prefetch
// reverted): BK=64, 4 waves, 2 blocks/CU, counted vmcnt. N=1024 GEMMs only.
// EPI: 3 +x(flag dtype)->bf16 | 4 +bias,relu->bf16 | 5 +bias+addbf16 -> out
// ---------------------------------------------------------------------------
template<int EPI, int LNBX>
__global__ __launch_bounds__(256, 2)
void gemm_dp(const u16* __restrict__ A, const u16* __restrict__ Bc,
             const u16* __restrict__ Braw, int M, int N, int K,
             const u16* __restrict__ bias, const u16* __restrict__ addbf,
             const float* __restrict__ addf, const int* __restrict__ dtflag,
             void* __restrict__ Cp, void* __restrict__ Cp2)
{
  __shared__ __align__(16) u16 sA[2][128 * 64];   // 32 KiB
  __shared__ __align__(16) u16 sB[2][128 * 64];   // 32 KiB
  (void)M;
  const int fl = *dtflag;
  const u16* __restrict__ B = fl ? Bc : Braw;
  const int tid = threadIdx.x;
  const int lane = tid & 63;
  const int w = tid >> 6;                       // 0..3
  const int b = blockIdx.x;
  const int wg = (b & 7) * ((int)gridDim.x >> 3) + (b >> 3);  // XCD swizzle
  const int bx = wg & ((1 << LNBX) - 1);
  const int by = wg >> LNBX;
  const int m0 = by * 128;
  const int n0 = bx * 128;
  const int wm = (w & 1) * 64;
  const int wn = (w >> 1) * 64;
  const int r = lane & 15;
  const int q = lane >> 4;
  const int r7 = lane & 7;
  const int srow = lane >> 3;                          // 0..7
  const int schunk = ((lane & 7) ^ (srow & 7)) << 3;   // inverse-swizzled src

  // stage one 128x64 tile: 4 g2l16/wave, row-group = j*4 + w (8 rows each)
  auto stage = [&](u16* dst, const u16* gbase, int ld) {
#pragma unroll
    for (int j = 0; j < 4; ++j) {
      u16* l = dst + ((j * 4 + w) * 8) * 64;             // wave-uniform base
      const u16* g = gbase + (size_t)((j * 4 + w) * 8 + srow) * ld + schunk;
      g2l16(g, l);
    }
  };
  const u16* gA = A + (size_t)m0 * K;
  const u16* gB = B + (size_t)n0 * K;

  f32x4 acc[4][4];
#pragma unroll
  for (int i = 0; i < 4; ++i)
#pragma unroll
    for (int j = 0; j < 4; ++j)
#pragma unroll
      for (int t = 0; t < 4; ++t) acc[i][j][t] = 0.f;

  const int nk = K >> 6;
  // prologue: A(0), B(0), A(1); wait A(0)+B(0), leave A(1) in flight
  stage(&sA[0][0], gA, K);
  stage(&sB[0][0], gB, K);
  if (nk > 1) {
    stage(&sA[1][0], gA + 64, K);
    asm volatile("s_waitcnt vmcnt(4)" ::: "memory");
  } else {
    asm volatile("s_waitcnt vmcnt(0)" ::: "memory");
  }
  SBAR0();
  __builtin_amdgcn_s_barrier();
  SBAR0();

  for (int kt = 0; kt < nk; ++kt) {
    const int c = kt & 1;
    bf16x8 af[4][2], b01[2][2], b23[2][2];

    // ---------- Phase 1: read af + b01; stage B(kt+1) -> c^1 ----------
#pragma unroll
    for (int mf = 0; mf < 4; ++mf)
#pragma unroll
      for (int ks = 0; ks < 2; ++ks)
        af[mf][ks] = *(const bf16x8*)&sA[c][(wm + mf * 16 + r) * 64
                        + ((((ks << 2) + q) ^ r7) << 3)];
#pragma unroll
    for (int nf = 0; nf < 2; ++nf)
#pragma unroll
      for (int ks = 0; ks < 2; ++ks)
        b01[nf][ks] = *(const bf16x8*)&sB[c][(wn + nf * 16 + r) * 64
                        + ((((ks << 2) + q) ^ r7) << 3)];
    if (kt + 1 < nk) stage(&sB[c ^ 1][0], gB + (size_t)(kt + 1) * 64, K);
    SBAR0();
    __builtin_amdgcn_s_barrier();
    SBAR0();
    __builtin_amdgcn_s_setprio(1);
#pragma unroll
    for (int mf = 0; mf < 4; ++mf)
#pragma unroll
      for (int nf = 0; nf < 2; ++nf)
#pragma unroll
        for (int ks = 0; ks < 2; ++ks)
          acc[mf][nf] = __builtin_amdgcn_mfma_f32_16x16x32_bf16(
              af[mf][ks], b01[nf][ks], acc[mf][nf], 0, 0, 0);
    __builtin_amdgcn_s_setprio(0);
    SBAR0();

    // ---------- Phase 2: read b23; stage A(kt+2) -> c; counted vmcnt ----------
#pragma unroll
    for (int nf = 0; nf < 2; ++nf)
#pragma unroll
      for (int ks = 0; ks < 2; ++ks)
        b23[nf][ks] = *(const bf16x8*)&sB[c][(wn + (nf + 2) * 16 + r) * 64
                        + ((((ks << 2) + q) ^ r7) << 3)];
    if (kt + 2 < nk) stage(&sA[c][0], gA + (size_t)(kt + 2) * 64, K);
    if (kt + 2 < nk) asm volatile("s_waitcnt vmcnt(4)" ::: "memory");
    else             asm volatile("s_waitcnt vmcnt(0)" ::: "memory");
    SBAR0();
    __builtin_amdgcn_s_barrier();
    SBAR0();
    __builtin_amdgcn_s_setprio(1);
#pragma unroll
    for (int mf = 0; mf < 4; ++mf)
#pragma unroll
      for (int nf = 0; nf < 2; ++nf)
#pragma unroll
        for (int ks = 0; ks < 2; ++ks)
          acc[mf][nf + 2] = __builtin_amdgcn_mfma_f32_16x16x32_bf16(
              af[mf][ks], b23[nf][ks], acc[mf][nf + 2], 0, 0, 0);
    __builtin_amdgcn_s_setprio(0);
    SBAR0();
  }

  // ---- LDS-transpose epilogue (per-wave 64x64 region, stride 68 f32) ----
  __syncthreads();
  float* ep = (w < 2) ? ((float*)&sA[0][0] + w * 2048)
                      : ((float*)&sB[0][0] + (w - 2) * 2048);
  const int r2 = lane >> 2;
  const int ccol = ((lane & 3) ^ (r2 & 3)) * 16;
#pragma unroll
  for (int i = 0; i < 4; ++i) {
#pragma unroll
    for (int j = 0; j < 4; ++j)
#pragma unroll
      for (int t = 0; t < 4; ++t)
        ep[(q * 4 + t) * 68 + j * 16 + r] = acc[i][j][t];
    f32x4 w0 = *(const f32x4*)&ep[r2 * 68 + ccol + 0];
    f32x4 w1 = *(const f32x4*)&ep[r2 * 68 + ccol + 4];
    f32x4 w2 = *(const f32x4*)&ep[r2 * 68 + ccol + 8];
    f32x4 w3 = *(const f32x4*)&ep[r2 * 68 + ccol + 12];
    float vv[16];
#pragma unroll
    for (int k = 0; k < 4; ++k) {
      vv[k] = w0[k]; vv[4 + k] = w1[k]; vv[8 + k] = w2[k]; vv[12 + k] = w3[k];
    }
    const int row = m0 + wm + i * 16 + r2;
    const int colg = n0 + wn + ccol;
    const size_t idx = (size_t)row * N + colg;
    if (EPI == 3) {               // h = x + v -> bf16
      float ax[16];
      if (fl) {
        f32x4 a0 = *(const f32x4*)&addf[idx];
        f32x4 a1 = *(const f32x4*)&addf[idx + 4];
        f32x4 a2 = *(const f32x4*)&addf[idx + 8];
        f32x4 a3 = *(const f32x4*)&addf[idx + 12];
#pragma unroll
        for (int k = 0; k < 4; ++k) {
          ax[k] = a0[k]; ax[4 + k] = a1[k]; ax[8 + k] = a2[k]; ax[12 + k] = a3[k];
        }
      } else {
        u16x8 a0 = *(const u16x8*)&addbf[idx];
        u16x8 a1 = *(const u16x8*)&addbf[idx + 8];
#pragma unroll
        for (int k = 0; k < 8; ++k) { ax[k] = bf2f(a0[k]); ax[8 + k] = bf2f(a1[k]); }
      }
      u16x8 o0, o1;
#pragma unroll
      for (int k = 0; k < 8; ++k) {
        o0[k] = f2bf(vv[k] + ax[k]); o1[k] = f2bf(vv[8 + k] + ax[8 + k]);
      }
      *(u16x8*)&((u16*)Cp)[idx] = o0;
      *(u16x8*)&((u16*)Cp)[idx + 8] = o1;
    } else if (EPI == 4) {               // relu(v + b1) -> bf16
      u16x8 b0 = *(const u16x8*)&bias[colg];
      u16x8 b1 = *(const u16x8*)&bias[colg + 8];
      u16x8 o0, o1;
#pragma unroll
      for (int k = 0; k < 8; ++k) {
        o0[k] = f2bf(fmaxf(vv[k] + bf2f(b0[k]), 0.f));
        o1[k] = f2bf(fmaxf(vv[8 + k] + bf2f(b1[k]), 0.f));
      }
      *(u16x8*)&((u16*)Cp)[idx] = o0;
      *(u16x8*)&((u16*)Cp)[idx + 8] = o1;
    } else {                             // EPI 5: out = h(bf16) + v + b2
      u16x8 b0 = *(const u16x8*)&bias[colg];
      u16x8 b1 = *(const u16x8*)&bias[colg + 8];
      u16x8 a0 = *(const u16x8*)&addbf[idx];
      u16x8 a1 = *(const u16x8*)&addbf[idx + 8];
      float r0[8], r1[8];
#pragma unroll
      for (int k = 0; k < 8; ++k) {
        r0[k] = vv[k] + bf2f(b0[k]) + bf2f(a0[k]);
        r1[k] = vv[8 + k] + bf2f(b1[k]) + bf2f(a1[k]);
      }
      if (fl) {
        f32x4 f0, f1, f2, f3;
#pragma unroll
        for (int k = 0; k < 4; ++k) { f0[k] = r0[k]; f1[k] = r0[4 + k]; f2[k] = r1[k]; f3[k] = r1[4 + k]; }
        *(f32x4*)&((float*)Cp)[idx] = f0;
        *(f32x4*)&((float*)Cp)[idx + 4] = f1;
        *(f32x4*)&((float*)Cp)[idx + 8] = f2;
        *(f32x4*)&((float*)Cp)[idx + 12] = f3;
      } else {
        u16x8 o0, o1;
#pragma unroll
        for (int k = 0; k < 8; ++k) { o0[k] = f2bf(r0[k]); o1[k] = f2bf(r1[k]); }
        *(u16x8*)&((u16*)Cp)[idx] = o0;
        *(u16x8*)&((u16*)Cp)[idx + 8] = o1;
      }
    }
  }
}

// ---------------------------------------------------------------------------
// Single-K-tile GEMM for dt (M=8192, N=2048, K=64). Stage once -> one
// barrier -> 32 MFMA -> softplus epilogue. No pipeline (write-bound op).
// ---------------------------------------------------------------------------
template<int LNBX>
__global__ __launch_bounds__(256, 2)
void gemm_k64(const u16* __restrict__ A, const u16* __restrict__ Bc,
              const u16* __restrict__ Braw, const int* __restrict__ dtflag,
              const u16* __restrict__ bias, u16* __restrict__ Cp)
{
  __shared__ __align__(16) u16 sA[128 * 64];   // 16 KiB
  __shared__ __align__(16) u16 sB[128 * 64];   // 16 KiB
  const int fl = *dtflag;
  const u16* __restrict__ B = fl ? Bc : Braw;
  const int tid = threadIdx.x;
  const int lane = tid & 63;
  const int w = tid >> 6;
  const int b = blockIdx.x;
  const int wg = (b & 7) * ((int)gridDim.x >> 3) + (b >> 3);
  const int bx = wg & ((1 << LNBX) - 1);
  const int by = wg >> LNBX;
  const int m0 = by * 128;
  const int n0 = bx * 128;
  const int wm = (w & 1) * 64;
  const int wn = (w >> 1) * 64;
  const int r = lane & 15;
  const int q = lane >> 4;
  const int r7 = lane & 7;
  const int srow = lane >> 3;
  const int schunk = ((lane & 7) ^ (srow & 7)) << 3;

  auto stage = [&](u16* dst, const u16* gbase) {
#pragma unroll
    for (int j = 0; j < 4; ++j) {
      u16* l = dst + ((j * 4 + w) * 8) * 64;
      const u16* g = gbase + (size_t)((j * 4 + w) * 8 + srow) * 64 + schunk;
      g2l16(g, l);
    }
  };
  stage(&sA[0], A + (size_t)m0 * 64);
  stage(&sB[0], B + (size_t)n0 * 64);
  asm volatile("s_waitcnt vmcnt(0)" ::: "memory");
  SBAR0();
  __builtin_amdgcn_s_barrier();
  SBAR0();

  f32x4 acc[4][4];
#pragma unroll
  for (int i = 0; i < 4; ++i)
#pragma unroll
    for (int j = 0; j < 4; ++j)
#pragma unroll
      for (int t = 0; t < 4; ++t) acc[i][j][t] = 0.f;

  bf16x8 af[4][2], bfv[4][2];
#pragma unroll
  for (int mf = 0; mf < 4; ++mf)
#pragma unroll
    for (int ks = 0; ks < 2; ++ks)
      af[mf][ks] = *(const bf16x8*)&sA[(wm + mf * 16 + r) * 64
                      + ((((ks << 2) + q) ^ r7) << 3)];
#pragma unroll
  for (int nf = 0; nf < 4; ++nf)
#pragma unroll
    for (int ks = 0; ks < 2; ++ks)
      bfv[nf][ks] = *(const bf16x8*)&sB[(wn + nf * 16 + r) * 64
                      + ((((ks << 2) + q) ^ r7) << 3)];
#pragma unroll
  for (int mf = 0; mf < 4; ++mf)
#pragma unroll
    for (int nf = 0; nf < 4; ++nf)
#pragma unroll
      for (int ks = 0; ks < 2; ++ks)
        acc[mf][nf] = __builtin_amdgcn_mfma_f32_16x16x32_bf16(
            af[mf][ks], bfv[nf][ks], acc[mf][nf], 0, 0, 0);

  // ---- LDS-transpose epilogue + softplus ----
  __syncthreads();
  float* ep = (w < 2) ? ((float*)&sA[0] + w * 2048)
                      : ((float*)&sB[0] + (w - 2) * 2048);
  const int r2 = lane >> 2;
  const int ccol = ((lane & 3) ^ (r2 & 3)) * 16;
#pragma unroll
  for (int i = 0; i < 4; ++i) {
#pragma unroll
    for (int j = 0; j < 4; ++j)
#pragma unroll
      for (int t = 0; t < 4; ++t)
        ep[(q * 4 + t) * 68 + j * 16 + r] = acc[i][j][t];
    f32x4 w0 = *(const f32x4*)&ep[r2 * 68 + ccol + 0];
    f32x4 w1 = *(const f32x4*)&ep[r2 * 68 + ccol + 4];
    f32x4 w2 = *(const f32x4*)&ep[r2 * 68 + ccol + 8];
    f32x4 w3 = *(const f32x4*)&ep[r2 * 68 + ccol + 12];
    float vv[16];
#pragma unroll
    for (int k = 0; k < 4; ++k) {
      vv[k] = w0[k]; vv[4 + k] = w1[k]; vv[8 + k] = w2[k]; vv[12 + k] = w3[k];
    }
    const int row = m0 + wm + i * 16 + r2;
    const int colg = n0 + wn + ccol;
    const size_t idx = (size_t)row * DI + colg;
    u16x8 b0 = *(const u16x8*)&bias[colg];
    u16x8 b1 = *(const u16x8*)&bias[colg + 8];
    u16x8 o0, o1;
#pragma unroll
    for (int k = 0; k < 8; ++k) {
      float v0 = vv[k] + bf2f(b0[k]);
      float v1 = vv[8 + k] + bf2f(b1[k]);
      v0 = (v0 > 15.f) ? v0 : __logf(1.f + __expf(v0));
      v1 = (v1 > 15.f) ? v1 : __logf(1.f + __expf(v1));
      o0[k] = f2bf(v0); o1[k] = f2bf(v1);
    }
    *(u16x8*)&Cp[idx] = o0;
    *(u16x8*)&Cp[idx + 8] = o1;
  }
}

// ---------------------------------------------------------------------------
// x_proj split-K: part[z] = u[:, z*256:(z+1)*256] @ w_xproj[:, same]^T
// ---------------------------------------------------------------------------
__global__ __launch_bounds__(256, 2)
void xproj_splitk(const u16* __restrict__ A, const u16* __restrict__ Bc,
                  const u16* __restrict__ Braw, const int* __restrict__ dtflag,
                  float* __restrict__ part)
{
  __shared__ __align__(16) u16 sA[2][128 * 32];
  __shared__ __align__(16) u16 sB[2][128 * 32];
  const int fl = *dtflag;
  const u16* __restrict__ B = fl ? Bc : Braw;
  const int tid = threadIdx.x;
  const int kz = blockIdx.x;           // 0..7
  const int m0 = blockIdx.y * 128;
  const int kbase = kz * 256;
  const int lane = tid & 63;
  const int wv = tid >> 6;
  const int wm = (wv & 1) * 64;
  const int wn = (wv >> 1) * 64;
  const int r = lane & 15;
  const int q = lane >> 4;
  const int rsw = (r >> 1) & 3;
  const int pr = lane >> 2;
  const int kc = (lane & 3) ^ ((pr >> 1) & 3);
  const int pk = kc * 8;

  u16* lA0[2] = { &sA[0][(wv * 2 + 0) * 512], &sA[1][(wv * 2 + 0) * 512] };
  u16* lA1[2] = { &sA[0][(wv * 2 + 1) * 512], &sA[1][(wv * 2 + 1) * 512] };
  u16* lB0[2] = { &sB[0][(wv * 2 + 0) * 512], &sB[1][(wv * 2 + 0) * 512] };
  u16* lB1[2] = { &sB[0][(wv * 2 + 1) * 512], &sB[1][(wv * 2 + 1) * 512] };
  int br0 = wv * 32 + pr;      if (br0 > 67) br0 = 67;   // junk cols unused
  int br1 = wv * 32 + 16 + pr; if (br1 > 67) br1 = 67;
  const u16* gA0 = A + (size_t)(m0 + wv * 32 + pr) * DI + kbase + pk;
  const u16* gA1 = gA0 + (size_t)16 * DI;
  const u16* gB0 = B + (size_t)br0 * DI + kbase + pk;
  const u16* gB1 = B + (size_t)br1 * DI + kbase + pk;

  f32x4 acc[4][4];
#pragma unroll
  for (int i = 0; i < 4; ++i)
#pragma unroll
    for (int j = 0; j < 4; ++j)
#pragma unroll
      for (int t = 0; t < 4; ++t) acc[i][j][t] = 0.f;

  g2l16(gA0, lA0[0]); g2l16(gA1, lA1[0]);
  g2l16(gB0, lB0[0]); g2l16(gB1, lB1[0]);

  for (int kt = 0; kt < 8; ++kt) {
    const int cur = kt & 1;
    __syncthreads();
    bf16x8 af[4], bfr[4];
#pragma unroll
    for (int i = 0; i < 4; ++i)
      af[i] = *reinterpret_cast<const bf16x8*>(
          &sA[cur][(wm + i * 16 + r) * 32 + (q ^ rsw) * 8]);
#pragma unroll
    for (int j = 0; j < 4; ++j)
      bfr[j] = *reinterpret_cast<const bf16x8*>(
          &sB[cur][(wn + j * 16 + r) * 32 + (q ^ rsw) * 8]);
    if (kt + 1 < 8) {
      gA0 += 32; gA1 += 32; gB0 += 32; gB1 += 32;
      g2l16(gA0, lA0[cur ^ 1]); g2l16(gA1, lA1[cur ^ 1]);
      g2l16(gB0, lB0[cur ^ 1]); g2l16(gB1, lB1[cur ^ 1]);
    }
#pragma unroll
    for (int i = 0; i < 4; ++i)
#pragma unroll
      for (int j = 0; j < 4; ++j)
        acc[i][j] = __builtin_amdgcn_mfma_f32_16x16x32_bf16(af[i], bfr[j], acc[i][j], 0, 0, 0);
  }

#pragma unroll
  for (int i = 0; i < 4; ++i)
#pragma unroll
    for (int j = 0; j < 4; ++j)
#pragma unroll
      for (int t = 0; t < 4; ++t) {
        const int row = m0 + wm + i * 16 + q * 4 + t;
        const int col = wn + j * 16 + r;
        if (col < NXP)
          part[((size_t)kz * NTOK + row) * NXP + col] = acc[i][j][t];
      }
}

// Reduce partials: cols 0..63 -> dtraw bf16 [NTOK,64]; 64..67 -> bc f32 [NTOK,4]
__global__ __launch_bounds__(256)
void xreduce_kernel(const float* __restrict__ part, u16* __restrict__ dtraw,
                    float* __restrict__ bc)
{
  const int i = blockIdx.x * 256 + threadIdx.x;
  if (i >= NTOK * NXP) return;
  const int row = i / NXP, col = i - row * NXP;
  float s = 0.f;
#pragma unroll
  for (int z = 0; z < 8; ++z) s += part[(size_t)z * NTOK * NXP + i];
  if (col < DTR) dtraw[(size_t)row * DTR + col] = f2bf(s);
  else           bc[row * 4 + (col - DTR)] = s;
}

// ---------------------------------------------------------------------------
// Depthwise causal conv + bias + SiLU, 16 tokens per block, window kept
// in registers (reads each xp row ~1.2x instead of 4x).
// ---------------------------------------------------------------------------
#define CTT 16
__global__ __launch_bounds__(256)
void conv_silu_tok(const u16* __restrict__ xp, const u16* __restrict__ cwT,
                   const u16* __restrict__ cb, u16* __restrict__ u)
{
  const int tok0 = blockIdx.x * CTT;        // global token of chunk start
  const int t0 = tok0 & (SEQ - 1);          // position within sequence
  const int d0 = threadIdx.x * 8;
  float w[4][8], cbv[8];
#pragma unroll
  for (int j = 0; j < 4; ++j) {
    u16x8 wv = *(const u16x8*)(cwT + j * DI + d0);
#pragma unroll
    for (int k = 0; k < 8; ++k) w[j][k] = bf2f(wv[k]);
  }
  u16x8 cbb = *(const u16x8*)(cb + d0);
#pragma unroll
  for (int k = 0; k < 8; ++k) cbv[k] = bf2f(cbb[k]);
  float xm0[8], xm1[8], xm2[8];             // x[t-3], x[t-2], x[t-1]
#pragma unroll
  for (int k = 0; k < 8; ++k) { xm0[k] = 0.f; xm1[k] = 0.f; xm2[k] = 0.f; }
  if (t0 != 0) {                            // chunk interior: all 3 priors valid
    u16x8 a = *(const u16x8*)(xp + (size_t)(tok0 - 3) * DI + d0);
    u16x8 bb = *(const u16x8*)(xp + (size_t)(tok0 - 2) * DI + d0);
    u16x8 c = *(const u16x8*)(xp + (size_t)(tok0 - 1) * DI + d0);
#pragma unroll
    for (int k = 0; k < 8; ++k) {
      xm0[k] = bf2f(a[k]); xm1[k] = bf2f(bb[k]); xm2[k] = bf2f(c[k]);
    }
  }
#pragma unroll
  for (int i = 0; i < CTT; ++i) {
    u16x8 xv = *(const u16x8*)(xp + (size_t)(tok0 + i) * DI + d0);
    float xc[8];
    u16x8 o;
#pragma unroll
    for (int k = 0; k < 8; ++k) {
      xc[k] = bf2f(xv[k]);
      const float a = cbv[k] + w[0][k] * xm0[k] + w[1][k] * xm1[k]
                    + w[2][k] * xm2[k] + w[3][k] * xc[k];
      const float sg = 1.f / (1.f + __expf(-a));
      o[k] = f2bf(a * sg);
    }
    *(u16x8*)(u + (size_t)(tok0 + i) * DI + d0) = o;
#pragma unroll
    for (int k = 0; k < 8; ++k) { xm0[k] = xm1[k]; xm1[k] = xm2[k]; xm2[k] = xc[k]; }
  }
}

// ---------------------------------------------------------------------------
// Chunked SSM scan (N=2 states), 4 channels per thread, CHUNK=32.
// ---------------------------------------------------------------------------
__global__ __launch_bounds__(256)
void scan_pass1(const u16* __restrict__ dtb, const u16* __restrict__ ub,
                const float* __restrict__ bc, const u16* __restrict__ a_log,
                float* __restrict__ S, float* __restrict__ hf0, float* __restrict__ hf1)
{
  const int g4 = blockIdx.x * 256 + threadIdx.x;   // NCHK*NCH/4
  const int chg = g4 & (NCH / 4 - 1);
  const int c = g4 >> 10;
  const int ch0 = chg * 4;
  const int b = ch0 >> 11;
  const int d0 = ch0 & (DI - 1);
  u16x8 av = *(const u16x8*)(a_log + d0 * 2);
  float A0[4], A1[4];
#pragma unroll
  for (int k = 0; k < 4; ++k) {
    A0[k] = -__expf(bf2f(av[2 * k]));
    A1[k] = -__expf(bf2f(av[2 * k + 1]));
  }
  float h0[4] = {0.f, 0.f, 0.f, 0.f}, h1[4] = {0.f, 0.f, 0.f, 0.f};
  float s[4] = {0.f, 0.f, 0.f, 0.f};
  const int row0 = b * SEQ + c * CHUNK;
  for (int i = 0; i < CHUNK; ++i) {
    const size_t row = row0 + i;
    u16x4 dtv = *(const u16x4*)(dtb + row * DI + d0);
    u16x4 uv  = *(const u16x4*)(ub + row * DI + d0);
    f32x2 Bv = *(const f32x2*)(bc + row * 4);
#pragma unroll
    for (int k = 0; k < 4; ++k) {
      const float dt = bf2f(dtv[k]);
      const float dtu = dt * bf2f(uv[k]);
      h0[k] = __expf(A0[k] * dt) * h0[k] + dtu * Bv[0];
      h1[k] = __expf(A1[k] * dt) * h1[k] + dtu * Bv[1];
      s[k] += dt;
    }
  }
  const size_t g0 = (size_t)c * NCH + ch0;
  *(f32x4*)(S + g0)   = f32x4{s[0], s[1], s[2], s[3]};
  *(f32x4*)(hf0 + g0) = f32x4{h0[0], h0[1], h0[2], h0[3]};
  *(f32x4*)(hf1 + g0) = f32x4{h1[0], h1[1], h1[2], h1[3]};
}

__global__ __launch_bounds__(256)
void scan_pass2(const float* __restrict__ S, const float* __restrict__ hf0,
                const float* __restrict__ hf1, const u16* __restrict__ a_log,
                float* __restrict__ hi0, float* __restrict__ hi1)
{
  const int ch = blockIdx.x * 256 + threadIdx.x;  // NCH
  const int d = ch & (DI - 1);
  const float A0 = -__expf(bf2f(a_log[d * 2 + 0]));
  const float A1 = -__expf(bf2f(a_log[d * 2 + 1]));
  float h0 = 0.f, h1 = 0.f;
  size_t g = ch;
  float sv = S[g], f0 = hf0[g], f1 = hf1[g];
  for (int c = 0; c < NCHK; ++c) {
    float svn = 0.f, f0n = 0.f, f1n = 0.f;
    if (c + 1 < NCHK) {
      const size_t gn = g + NCH;
      svn = S[gn]; f0n = hf0[gn]; f1n = hf1[gn];
    }
    hi0[g] = h0; hi1[g] = h1;
    h0 = __expf(A0 * sv) * h0 + f0;
    h1 = __expf(A1 * sv) * h1 + f1;
    sv = svn; f0 = f0n; f1 = f1n;
    g += NCH;
  }
}

__global__ __launch_bounds__(256)
void scan_pass3(const u16* __restrict__ dtb, const u16* __restrict__ ub,
                const float* __restrict__ bc, const u16* __restrict__ zbuf,
                const u16* __restrict__ a_log, const u16* __restrict__ d_skip,
                const float* __restrict__ hi0, const float* __restrict__ hi1,
                u16* __restrict__ yb)
{
  const int g4 = blockIdx.x * 256 + threadIdx.x;
  const int chg = g4 & (NCH / 4 - 1);
  const int c = g4 >> 10;
  const int ch0 = chg * 4;
  const int b = ch0 >> 11;
  const int d0 = ch0 & (DI - 1);
  u16x8 av = *(const u16x8*)(a_log + d0 * 2);
  u16x4 dkv = *(const u16x4*)(d_skip + d0);
  float A0[4], A1[4], dsk[4];
#pragma unroll
  for (int k = 0; k < 4; ++k) {
    A0[k] = -__expf(bf2f(av[2 * k]));
    A1[k] = -__expf(bf2f(av[2 * k + 1]));
    dsk[k] = bf2f(dkv[k]);
  }
  const size_t g0 = (size_t)c * NCH + ch0;
  f32x4 h0v = *(const f32x4*)(hi0 + g0);
  f32x4 h1v = *(const f32x4*)(hi1 + g0);
  float h0[4], h1[4];
#pragma unroll
  for (int k = 0; k < 4; ++k) { h0[k] = h0v[k]; h1[k] = h1v[k]; }
  const int row0 = b * SEQ + c * CHUNK;
  for (int i = 0; i < CHUNK; ++i) {
    const size_t row = row0 + i;
    u16x4 dtv = *(const u16x4*)(dtb + row * DI + d0);
    u16x4 uv  = *(const u16x4*)(ub + row * DI + d0);
    u16x4 zv  = *(const u16x4*)(zbuf + row * DI + d0);
    f32x4 bcv = *(const f32x4*)(bc + row * 4);
    u16x4 o;
#pragma unroll
    for (int k = 0; k < 4; ++k) {
      const float dt = bf2f(dtv[k]);
      const float uu = bf2f(uv[k]);
      const float dtu = dt * uu;
      h0[k] = __expf(A0[k] * dt) * h0[k] + dtu * bcv[0];
      h1[k] = __expf(A1[k] * dt) * h1[k] + dtu * bcv[1];
      const float y = h0[k] * bcv[2] + h1[k] * bcv[3];
      const float z = bf2f(zv[k]);
      const float sz = z / (1.f + __expf(-z));
      o[k] = f2bf((y + dsk[k] * uu) * sz);
    }
    *(u16x4*)(yb + row * DI + d0) = o;    // in-place over dtb: ok
  }
}

// ---------------------------------------------------------------------------
extern "C" void kernel_launch(void* const* d_in, const int* in_sizes, int n_in,
                              void* d_out, int out_size, void* d_ws, size_t ws_size,
                              hipStream_t stream)
{
  const void* x       = d_in[0];
  const void* w_in    = d_in[1];
  const void* conv_w  = d_in[2];
  const void* conv_b  = d_in[3];
  const void* w_xproj = d_in[4];
  const void* w_dt    = d_in[5];
  const void* b_dt    = d_in[6];
  const void* a_log   = d_in[7];
  const void* d_skip  = d_in[8];
  const void* w_out   = d_in[9];
  const void* ln1_g   = d_in[10];
  const void* ln1_b   = d_in[11];
  const void* ln2_g   = d_in[12];
  const void* ln2_b   = d_in[13];
  const void* ffn_w1  = d_in[14];
  const void* ffn_b1  = d_in[15];
  const void* ffn_w2  = d_in[16];
  const void* ffn_b2  = d_in[17];
  char* ws = (char*)d_ws;

  // ---- workspace layout (high-water ~127 MB) ----
  const size_t o_flag  = 0;
  const size_t o_small = 256;
  const size_t o_cwout = o_small + 65536;
  const size_t o_cff1  = o_cwout + (size_t)DM * DI * 2;
  const size_t o_cff2  = o_cff1  + (size_t)DM * DM * 2;
  const size_t o_cxp   = o_cff2  + (size_t)DM * DM * 2;
  const size_t o_cwdt  = o_cxp   + (size_t)NXP * DI * 2;
  const size_t o_xn    = 9437184;                         // 16 MiB region
  const size_t o_xp    = o_xn + (size_t)NTOK * DM * 2;    // 32 MiB
  const size_t o_z     = o_xp + (size_t)NTOK * DI * 2;    // 32 MiB
  const size_t o_u     = o_z  + (size_t)NTOK * DI * 2;    // 32 MiB
  const size_t o_bc    = o_u  + (size_t)NTOK * DI * 2;    // 128 KiB
  const size_t SCN = (size_t)NCHK * NCH * 4;              // 2 MiB each
  const size_t o_S   = o_xn + 0 * SCN;
  const size_t o_hf0 = o_xn + 1 * SCN;
  const size_t o_hf1 = o_xn + 2 * SCN;
  const size_t o_hi0 = o_xn + 3 * SCN;
  const size_t o_hi1 = o_xn + 4 * SCN;

  int*   flagp   = (int*)(ws + o_flag);
  u16*   csmall  = (u16*)(ws + o_small);
  u16*   c_cwT   = csmall +     0;       // transposed conv weights [4][DI]
  u16*   c_convb = csmall +  8192;
  u16*   c_bdt   = csmall + 10240;
  u16*   c_alog  = csmall + 12288;
  u16*   c_dskip = csmall + 16384;
  u16*   c_ln1g  = csmall + 18432;
  u16*   c_ln1b  = csmall + 19456;
  u16*   c_ln2g  = csmall + 20480;
  u16*   c_ln2b  = csmall + 21504;
  u16*   c_fb1   = csmall + 22528;
  u16*   c_fb2   = csmall + 23552;
  u16*   c_wout  = (u16*)(ws + o_cwout);
  u16*   c_ff1   = (u16*)(ws + o_cff1);
  u16*   c_ff2   = (u16*)(ws + o_cff2);
  u16*   c_xproj = (u16*)(ws + o_cxp);
  u16*   c_wdt   = (u16*)(ws + o_cwdt);
  u16*   c_win   = (u16*)(ws + o_u);     // overlays u (dead until conv)
  u16*   xn      = (u16*)(ws + o_xn);
  u16*   xp      = (u16*)(ws + o_xp);
  u16*   zb      = (u16*)(ws + o_z);
  u16*   u       = (u16*)(ws + o_u);
  float* part    = (float*)(ws + o_xp);  // overlays xp (dead after conv)
  u16*   dtraw   = (u16*)(ws + o_xn);    // overlays xn (dead after in_proj)
  u16*   dtb     = xp;                   // overlays part (dead after reduce)
  u16*   yb      = xp;
  float* bc      = (float*)(ws + o_bc);
  float* S       = (float*)(ws + o_S);
  float* hf0     = (float*)(ws + o_hf0);
  float* hf1     = (float*)(ws + o_hf1);
  float* hi0     = (float*)(ws + o_hi0);
  float* hi1     = (float*)(ws + o_hi1);
  u16*   hb      = (u16*)(ws + o_z);     // h as bf16, overlays z (dead after pass3)
  u16*   hn      = (u16*)(ws + o_xn);    // overlays scan arrays (dead)
  u16*   f1      = (u16*)(ws + o_u);     // overlays u (dead)

  const dim3 blk(256);

  // 0) detect dtype; all param conversion in ONE launch
  detect_kernel<<<1, blk, 0, stream>>>((const u16*)x, flagp);
  convert_all<<<NBB + 96, blk, 0, stream>>>(
      (const float*)w_in, (const float*)w_xproj, (const float*)w_dt,
      (const float*)w_out, (const float*)ffn_w1, (const float*)ffn_w2,
      c_win, c_xproj, c_wdt, c_wout, c_ff1, c_ff2,
      conv_w, conv_b, b_dt, a_log, d_skip,
      ln1_g, ln1_b, ln2_g, ln2_b, ffn_b1, ffn_b2,
      csmall, flagp);

  // 1) LN1(x) -> xn
  ln_kernel<0><<<NTOK / 2, blk, 0, stream>>>(x, c_ln1g, c_ln1b, xn, flagp);
  // 2) fused in_proj: [xp | z] = xn @ w_in^T  (256x256 2-phase, grid 32*16=512)
  gemm256_kernel<6, 4><<<512, dim3(512), 0, stream>>>(
      xn, c_win, (const u16*)w_in, NTOK, 2 * DI, DM, flagp, xp, zb);
  // 3) u = silu(conv(xp) + conv_b)   (16 tokens/block, register window)
  conv_silu_tok<<<NTOK / CTT, blk, 0, stream>>>(xp, c_cwT, c_convb, u);
  // 4) x_proj split-K (partials) + reduce -> dtraw (bf16), bc (f32)
  xproj_splitk<<<dim3(8, 64), blk, 0, stream>>>(u, c_xproj, (const u16*)w_xproj,
                                                flagp, part);
  xreduce_kernel<<<(NTOK * NXP + 255) / 256, blk, 0, stream>>>(part, dtraw, bc);
  // 5) dt = softplus(dtraw @ w_dt^T + b_dt)   (single-K-tile kernel)
  gemm_k64<4><<<1024, blk, 0, stream>>>(dtraw, c_wdt, (const u16*)w_dt,
                                        flagp, c_bdt, dtb);
  // 6) chunked scan -> yb = (y + d_skip*u) * silu(z)
  scan_pass1<<<NCHK * NCH / 4 / 256, blk, 0, stream>>>(dtb, u, bc, c_alog, S, hf0, hf1);
  scan_pass2<<<NCH / 256, blk, 0, stream>>>(S, hf0, hf1, c_alog, hi0, hi1);
  scan_pass3<<<NCHK * NCH / 4 / 256, blk, 0, stream>>>(dtb, u, bc, zb, c_alog, c_dskip,
                                                       hi0, hi1, yb);
  // 7) h = bf16(x + yb @ w_out^T)   (dp, grid 64*8=512, nk=32)
  gemm_dp<3, 3><<<512, blk, 0, stream>>>(yb, c_wout, (const u16*)w_out,
                                         NTOK, DM, DI,
                                         nullptr, (const u16*)x, (const float*)x,
                                         flagp, hb, nullptr);
  // 8) LN2(h) -> hn   (bf16 input)
  ln_kernel<1><<<NTOK / 2, blk, 0, stream>>>(hb, c_ln2g, c_ln2b, hn, flagp);
  // 9) f1 = relu(hn @ ffn_w1^T + b1)   (dp, nk=16)
  gemm_dp<4, 3><<<512, blk, 0, stream>>>(hn, c_ff1, (const u16*)ffn_w1,
                                         NTOK, DM, DM,
                                         c_fb1, nullptr, nullptr, flagp, f1, nullptr);
  // 10) out = h + f1 @ ffn_w2^T + b2   (dp, nk=16)
  gemm_dp<5, 3><<<512, blk, 0, stream>>>(f1, c_ff2, (const u16*)ffn_w2,
                                         NTOK, DM, DM,
                                         c_fb2, hb, nullptr, flagp, d_out, nullptr);
}

// Round 9
// 426.602 us; speedup vs baseline: 1.0347x; 1.0157x over previous
//
#include <hip/hip_runtime.h>

typedef unsigned short u16;
typedef __bf16 bf16x8 __attribute__((ext_vector_type(8)));
typedef float f32x4 __attribute__((ext_vector_type(4)));
typedef float f32x2 __attribute__((ext_vector_type(2)));
typedef u16 u16x4 __attribute__((ext_vector_type(4)));
typedef u16 u16x8 __attribute__((ext_vector_type(8)));

// Problem constants
#define SEQ   4096
#define DM    1024
#define DI    2048
#define NTOK  8192      // BATCH * SEQ
#define NXP   68        // DT_RANK + 2*D_STATE
#define DTR   64        // DT_RANK
#define NCH   4096      // BATCH * DI channels for scan
#define CHUNK 32
#define NCHK  128       // SEQ / CHUNK

__device__ __forceinline__ float bf2f(u16 v) {
  union { unsigned u; float f; } x; x.u = ((unsigned)v) << 16; return x.f;
}
__device__ __forceinline__ u16 f2bf(float f) {
  unsigned u = __float_as_uint(f);
  return (u16)((u + 0x7FFFu + ((u >> 16) & 1u)) >> 16);   // RNE
}

// async global->LDS DMA, 16B/lane; LDS dest = wave-uniform base + lane*16
__device__ __forceinline__ void g2l16(const u16* g, u16* l) {
  __builtin_amdgcn_global_load_lds(
      (const __attribute__((address_space(1))) unsigned int*)g,
      (__attribute__((address_space(3))) unsigned int*)l, 16, 0, 0);
}

#define SBAR0() __builtin_amdgcn_sched_barrier(0)

// ---------------------------------------------------------------------------
// Input dtype detection (f32 inputs -> low u16 has huge bf16 exponents)
// ---------------------------------------------------------------------------
__global__ __launch_bounds__(256)
void detect_kernel(const u16* __restrict__ x, int* __restrict__ flag)
{
  __shared__ int tot;
  if (threadIdx.x == 0) tot = 0;
  __syncthreads();
  int cnt = 0;
  for (int i = threadIdx.x; i < 4096; i += 256) {
    const int e = (x[2 * i] >> 7) & 0xFF;
    if (e > 167) cnt++;
  }
  atomicAdd(&tot, cnt);
  __syncthreads();
  if (threadIdx.x == 0) flag[0] = (tot >= 8) ? 1 : 0;
}

// ---------------------------------------------------------------------------
// ONE conversion launch. Blocks < NBB: 6 big weights, 8 elems/thread (no-op
// when inputs are bf16). Blocks >= NBB: 11 small vectors incl. conv_w
// transpose to [4][DI] (always runs).
// ---------------------------------------------------------------------------
#define NW0 4194304   // w_in
#define NW1  139264   // w_xproj
#define NW2  131072   // w_dt
#define NW3 2097152   // w_out
#define NW4 1048576   // ffn_w1
#define NW5 1048576   // ffn_w2
#define NBB 4228      // ceil((sum NW)/8/256)
__global__ __launch_bounds__(256)
void convert_all(const float* __restrict__ s0, const float* __restrict__ s1,
                 const float* __restrict__ s2, const float* __restrict__ s3,
                 const float* __restrict__ s4, const float* __restrict__ s5,
                 u16* __restrict__ d0, u16* __restrict__ d1, u16* __restrict__ d2,
                 u16* __restrict__ d3, u16* __restrict__ d4, u16* __restrict__ d5,
                 const void* t0, const void* t1, const void* t2, const void* t3,
                 const void* t4, const void* t5, const void* t6, const void* t7,
                 const void* t8, const void* t9, const void* t10,
                 u16* __restrict__ dsm, const int* __restrict__ flag)
{
  if (blockIdx.x >= NBB) {
    const int i = (blockIdx.x - NBB) * 256 + threadIdx.x;
    if (i >= 24576) return;
    const void* src; int off; int dsti = i;
    if      (i < 8192)  { src = t0;  off = i;
                          dsti = (off & 3) * DI + (off >> 2); }  // conv_w -> [j][d]
    else if (i < 10240) { src = t1;  off = i - 8192; }   // conv_b
    else if (i < 12288) { src = t2;  off = i - 10240; }  // b_dt
    else if (i < 16384) { src = t3;  off = i - 12288; }  // a_log
    else if (i < 18432) { src = t4;  off = i - 16384; }  // d_skip
    else if (i < 19456) { src = t5;  off = i - 18432; }  // ln1_g
    else if (i < 20480) { src = t6;  off = i - 19456; }  // ln1_b
    else if (i < 21504) { src = t7;  off = i - 20480; }  // ln2_g
    else if (i < 22528) { src = t8;  off = i - 21504; }  // ln2_b
    else if (i < 23552) { src = t9;  off = i - 22528; }  // ffn_b1
    else                { src = t10; off = i - 23552; }  // ffn_b2
    dsm[dsti] = (*flag) ? f2bf(((const float*)src)[off]) : ((const u16*)src)[off];
    return;
  }
  if (*flag == 0) return;
  long e = ((long)blockIdx.x * 256 + threadIdx.x) * 8;
  const long c1 = NW0, c2 = c1 + NW1, c3 = c2 + NW2, c4 = c3 + NW3,
             c5 = c4 + NW4, c6 = c5 + NW5;
  if (e >= c6) return;
  const float* s; u16* d;
  if      (e < c1) { s = s0;          d = d0; }
  else if (e < c2) { s = s1; e -= c1; d = d1; }
  else if (e < c3) { s = s2; e -= c2; d = d2; }
  else if (e < c4) { s = s3; e -= c3; d = d3; }
  else if (e < c5) { s = s4; e -= c4; d = d4; }
  else             { s = s5; e -= c5; d = d5; }
  f32x4 a = *(const f32x4*)(s + e);
  f32x4 b = *(const f32x4*)(s + e + 4);
  u16x8 o;
#pragma unroll
  for (int k = 0; k < 4; ++k) { o[k] = f2bf(a[k]); o[4 + k] = f2bf(b[k]); }
  *(u16x8*)(d + e) = o;
}

// ---------------------------------------------------------------------------
// LayerNorm: 2 rows per block, 8 elems per thread, vectorized loads/stores.
// MODE 0: input dtype per runtime flag (LN1). MODE 1: bf16 always (LN2).
// ---------------------------------------------------------------------------
template<int MODE>
__global__ __launch_bounds__(256)
void ln_kernel(const void* __restrict__ xin, const u16* __restrict__ gw,
               const u16* __restrict__ bw, u16* __restrict__ outp,
               const int* __restrict__ flag)
{
  const int tid = threadIdx.x;
  const int sub = tid >> 7;                  // row within block
  const int col0 = (tid & 127) * 8;
  const int row = blockIdx.x * 2 + sub;
  const bool isf32 = (MODE == 0) ? (*flag != 0) : false;
  float v[8];
  if (isf32) {
    const float* xf = (const float*)xin + (size_t)row * DM + col0;
    f32x4 a = *(const f32x4*)xf, b2 = *(const f32x4*)(xf + 4);
#pragma unroll
    for (int k = 0; k < 4; ++k) { v[k] = a[k]; v[4 + k] = b2[k]; }
  } else {
    u16x8 xb = *(const u16x8*)((const u16*)xin + (size_t)row * DM + col0);
#pragma unroll
    for (int k = 0; k < 8; ++k) v[k] = bf2f(xb[k]);
  }
  float s = 0.f, s2 = 0.f;
#pragma unroll
  for (int k = 0; k < 8; ++k) { s += v[k]; s2 += v[k] * v[k]; }
#pragma unroll
  for (int off = 32; off > 0; off >>= 1) {
    s  += __shfl_down(s,  off);
    s2 += __shfl_down(s2, off);
  }
  __shared__ float red[4], red2[4];
  __shared__ f32x2 stat[2];
  const int wv = tid >> 6;
  if ((tid & 63) == 0) { red[wv] = s; red2[wv] = s2; }
  __syncthreads();
  if ((tid & 127) == 0) {
    float ts = red[sub * 2] + red[sub * 2 + 1];
    float t2 = red2[sub * 2] + red2[sub * 2 + 1];
    float mu = ts * (1.f / DM);
    float var = t2 * (1.f / DM) - mu * mu;
    stat[sub] = f32x2{mu, rsqrtf(var + 1e-5f)};
  }
  __syncthreads();
  const float mu = stat[sub][0], rs = stat[sub][1];
  u16x8 gv = *(const u16x8*)(gw + col0), bv = *(const u16x8*)(bw + col0);
  u16x8 o;
#pragma unroll
  for (int k = 0; k < 8; ++k)
    o[k] = f2bf((v[k] - mu) * rs * bf2f(gv[k]) + bf2f(bv[k]));
  *(u16x8*)(outp + (size_t)row * DM + col0) = o;
}

// ---------------------------------------------------------------------------
// 256x256 2-phase GEMM (in_proj). R8: removed explicit lgkmcnt(0)+sched
// fences before MFMA clusters — compiler emits fine-grained lgkmcnt(N) and
// can overlap ds_reads under MFMA (hand drain serialized the two pipes:
// 5505 cyc/K-tile ≈ 2480 MFMA + 2300 LDS, no overlap). Safety: every
// ds_read result is consumed by an MFMA before the next barrier, so
// compiler dependency-waits guarantee completion before any wave crosses
// that barrier and overwrites the region. vmcnt accounting unchanged.
// EPI 6: split store n0<DI -> Cp else Cp2, row stride DI.
// ---------------------------------------------------------------------------
template<int EPI, int LNBX>
__global__ __launch_bounds__(512, 2)
void gemm256_kernel(const u16* __restrict__ A, const u16* __restrict__ Bc,
                    const u16* __restrict__ Braw, int M, int N, int K,
                    const int* __restrict__ dtflag, void* __restrict__ Cp,
                    void* __restrict__ Cp2)
{
  __shared__ __align__(16) u16 sAB[2][2][2][128 * 64];  // [buf][mat][half]
  (void)M;
  const int fl = *dtflag;
  const u16* __restrict__ B = fl ? Bc : Braw;
  const int tid = threadIdx.x;
  const int w = tid >> 6;         // wave 0..7
  const int lane = tid & 63;
  const int b = blockIdx.x;
  const int wg = (b & 7) * (gridDim.x >> 3) + (b >> 3);  // bijective XCD swizzle
  const int bx = wg & ((1 << LNBX) - 1);
  const int by = wg >> LNBX;
  const int m0 = by * 256;
  const int n0 = bx * 256;
  const int wm = w >> 2;          // 0..1 : A half / 128-row slice
  const int wn = w & 3;           // 0..3 : 64-col slice
  const int r = lane & 15;
  const int q = lane >> 4;
  const int r7 = r & 7;
  const int srow = lane >> 3;                          // stage row in 8-row group
  const int schunk = ((lane & 7) ^ (srow & 7)) << 3;   // inverse-swizzled src chunk

  auto stageA = [&](int buf, int half, int kt) {
#pragma unroll
    for (int j = 0; j < 2; ++j) {
      u16* l = &sAB[buf][0][half][(w * 16 + j * 8) * 64];          // wave-uniform
      const u16* g = A + (size_t)(m0 + half * 128 + w * 16 + j * 8 + srow) * K
                       + (kt << 6) + schunk;
      g2l16(g, l);
    }
  };
  auto stageB = [&](int buf, int half, int kt) {
#pragma unroll
    for (int j = 0; j < 2; ++j) {
      u16* l = &sAB[buf][1][half][(w * 16 + j * 8) * 64];
      const u16* g = B + (size_t)(n0 + half * 128 + w * 16 + j * 8 + srow) * K
                       + (kt << 6) + schunk;
      g2l16(g, l);
    }
  };

  f32x4 acc[8][4];
#pragma unroll
  for (int i = 0; i < 8; ++i)
#pragma unroll
    for (int j = 0; j < 4; ++j)
#pragma unroll
      for (int t = 0; t < 4; ++t) acc[i][j][t] = 0.f;

  const int nk = K >> 6;
  // prologue: A(0) both halves, B(0) both halves, B(1) both halves.
  // vmcnt(4): oldest 8 (= A(0),B(0)) landed; B(1) stays in flight.
  stageA(0, 0, 0); stageA(0, 1, 0); stageB(0, 0, 0); stageB(0, 1, 0);
  if (nk > 1) { stageB(1, 0, 1); stageB(1, 1, 1); }
  if (nk > 1) asm volatile("s_waitcnt vmcnt(4)" ::: "memory");
  else        asm volatile("s_waitcnt vmcnt(0)" ::: "memory");
  SBAR0();
  __builtin_amdgcn_s_barrier();
  SBAR0();

  for (int kt = 0; kt < nk; ++kt) {
    const int c = kt & 1;
    const u16* bA = &sAB[c][0][wm][0];
    const u16* bB = &sAB[c][1][wn >> 1][0];
    const int rB = (wn & 1) * 64;
    bf16x8 af03[4][2], af47[4][2], b01[2][2], b23[2][2];

    // ---------- Phase 1: read af03 + b01 + b23; stage A(kt+1) -> c^1;
    //            MFMA (compiler interleaves reads under MFMA) ----------
#pragma unroll
    for (int mf = 0; mf < 4; ++mf)
#pragma unroll
      for (int ks = 0; ks < 2; ++ks)
        af03[mf][ks] = *(const bf16x8*)&bA[(mf * 16 + r) * 64
                          + ((((ks << 2) + q) ^ r7) << 3)];
#pragma unroll
    for (int nf = 0; nf < 2; ++nf)
#pragma unroll
      for (int ks = 0; ks < 2; ++ks) {
        b01[nf][ks] = *(const bf16x8*)&bB[(rB + nf * 16 + r) * 64
                          + ((((ks << 2) + q) ^ r7) << 3)];
        b23[nf][ks] = *(const bf16x8*)&bB[(rB + (nf + 2) * 16 + r) * 64
                          + ((((ks << 2) + q) ^ r7) << 3)];
      }
    if (kt + 1 < nk) { stageA(c ^ 1, 0, kt + 1); stageA(c ^ 1, 1, kt + 1); }
    __builtin_amdgcn_s_setprio(1);
#pragma unroll
    for (int mf = 0; mf < 4; ++mf)
#pragma unroll
      for (int nf = 0; nf < 2; ++nf)
#pragma unroll
        for (int ks = 0; ks < 2; ++ks) {
          acc[mf][nf] = __builtin_amdgcn_mfma_f32_16x16x32_bf16(
              af03[mf][ks], b01[nf][ks], acc[mf][nf], 0, 0, 0);
          acc[mf][nf + 2] = __builtin_amdgcn_mfma_f32_16x16x32_bf16(
              af03[mf][ks], b23[nf][ks], acc[mf][nf + 2], 0, 0, 0);
        }
    __builtin_amdgcn_s_setprio(0);

    // ---------- Phase 2: read af47 (pre-barrier, mat0: no hazard);
    //            barrier (B(c) WAR gate — P1 reads all consumed above);
    //            stage B(kt+2) -> c; MFMA ----------
#pragma unroll
    for (int mf = 0; mf < 4; ++mf)
#pragma unroll
      for (int ks = 0; ks < 2; ++ks)
        af47[mf][ks] = *(const bf16x8*)&bA[((mf + 4) * 16 + r) * 64
                          + ((((ks << 2) + q) ^ r7) << 3)];
    SBAR0();
    __builtin_amdgcn_s_barrier();   // all waves' b01/b23 reads complete
    SBAR0();
    if (kt + 2 < nk) { stageB(c, 0, kt + 2); stageB(c, 1, kt + 2); }
    __builtin_amdgcn_s_setprio(1);
#pragma unroll
    for (int mf = 0; mf < 4; ++mf)
#pragma unroll
      for (int nf = 0; nf < 2; ++nf)
#pragma unroll
        for (int ks = 0; ks < 2; ++ks) {
          acc[mf + 4][nf] = __builtin_amdgcn_mfma_f32_16x16x32_bf16(
              af47[mf][ks], b01[nf][ks], acc[mf + 4][nf], 0, 0, 0);
          acc[mf + 4][nf + 2] = __builtin_amdgcn_mfma_f32_16x16x32_bf16(
              af47[mf][ks], b23[nf][ks], acc[mf + 4][nf + 2], 0, 0, 0);
        }
    __builtin_amdgcn_s_setprio(0);
    SBAR0();
    if (kt + 2 < nk) asm volatile("s_waitcnt vmcnt(4)" ::: "memory");
    else             asm volatile("s_waitcnt vmcnt(0)" ::: "memory");
    SBAR0();
    __builtin_amdgcn_s_barrier();   // cross-wave: A(kt+1)+B(kt+1) visible
    SBAR0();
  }

  // ---- LDS-transpose epilogue (loop ended with full barrier + drain) ----
  float* ep = (float*)&sAB[0][0][0][0] + w * 4096;
  const int r2 = lane >> 2;
  const int ccol = ((lane & 3) ^ (r2 & 3)) * 16;
  u16* C6 = (n0 < DI) ? (u16*)Cp : (u16*)Cp2;
  const int c6off = (n0 < DI) ? 0 : DI;
#pragma unroll
  for (int mf = 0; mf < 8; ++mf) {
#pragma unroll
    for (int nf = 0; nf < 4; ++nf)
#pragma unroll
      for (int t = 0; t < 4; ++t)
        ep[(q * 4 + t) * 68 + nf * 16 + r] = acc[mf][nf][t];
    f32x4 w0 = *(const f32x4*)&ep[r2 * 68 + ccol + 0];
    f32x4 w1 = *(const f32x4*)&ep[r2 * 68 + ccol + 4];
    f32x4 w2 = *(const f32x4*)&ep[r2 * 68 + ccol + 8];
    f32x4 w3 = *(const f32x4*)&ep[r2 * 68 + ccol + 12];
    u16x8 o0, o1;
#pragma unroll
    for (int k = 0; k < 4; ++k) {
      o0[k] = f2bf(w0[k]); o0[4 + k] = f2bf(w1[k]);
      o1[k] = f2bf(w2[k]); o1[4 + k] = f2bf(w3[k]);
    }
    const int row = m0 + wm * 128 + mf * 16 + r2;
    const int colg = n0 + wn * 64 + ccol;
    const size_t cb = (size_t)row * DI + (colg - c6off);
    *(u16x8*)&C6[cb] = o0;
    *(u16x8*)&C6[cb + 8] = o1;
  }
}

// ---------------------------------------------------------------------------
// Deep-pipeline 128x128 GEMM "gemm_dp" (R4-measured version): BK=64, 4 waves,
// 2 blocks/CU, counted vmcnt. N=1024 GEMMs only.
// EPI: 3 +x(flag dtype)->bf16 | 4 +bias,relu->bf16 | 5 +bias+addbf16 -> out
// ---------------------------------------------------------------------------
template<int EPI, int LNBX>
__global__ __launch_bounds__(256, 2)
void gemm_dp(const u16* __restrict__ A, const u16* __restrict__ Bc,
             const u16* __restrict__ Braw, int M, int N, int K,
             const u16* __restrict__ bias, const u16* __restrict__ addbf,
             const float* __restrict__ addf, const int* __restrict__ dtflag,
             void* __restrict__ Cp, void* __restrict__ Cp2)
{
  __shared__ __align__(16) u16 sA[2][128 * 64];   // 32 KiB
  __shared__ __align__(16) u16 sB[2][128 * 64];   // 32 KiB
  (void)M;
  const int fl = *dtflag;
  const u16* __restrict__ B = fl ? Bc : Braw;
  const int tid = threadIdx.x;
  const int lane = tid & 63;
  const int w = tid >> 6;                       // 0..3
  const int b = blockIdx.x;
  const int wg = (b & 7) * ((int)gridDim.x >> 3) + (b >> 3);  // XCD swizzle
  const int bx = wg & ((1 << LNBX) - 1);
  const int by = wg >> LNBX;
  const int m0 = by * 128;
  const int n0 = bx * 128;
  const int wm = (w & 1) * 64;
  const int wn = (w >> 1) * 64;
  const int r = lane & 15;
  const int q = lane >> 4;
  const int r7 = lane & 7;
  const int srow = lane >> 3;                          // 0..7
  const int schunk = ((lane & 7) ^ (srow & 7)) << 3;   // inverse-swizzled src

  // stage one 128x64 tile: 4 g2l16/wave, row-group = j*4 + w (8 rows each)
  auto stage = [&](u16* dst, const u16* gbase, int ld) {
#pragma unroll
    for (int j = 0; j < 4; ++j) {
      u16* l = dst + ((j * 4 + w) * 8) * 64;             // wave-uniform base
      const u16* g = gbase + (size_t)((j * 4 + w) * 8 + srow) * ld + schunk;
      g2l16(g, l);
    }
  };
  const u16* gA = A + (size_t)m0 * K;
  const u16* gB = B + (size_t)n0 * K;

  f32x4 acc[4][4];
#pragma unroll
  for (int i = 0; i < 4; ++i)
#pragma unroll
    for (int j = 0; j < 4; ++j)
#pragma unroll
      for (int t = 0; t < 4; ++t) acc[i][j][t] = 0.f;

  const int nk = K >> 6;
  // prologue: A(0), B(0), A(1); wait A(0)+B(0), leave A(1) in flight
  stage(&sA[0][0], gA, K);
  stage(&sB[0][0], gB, K);
  if (nk > 1) {
    stage(&sA[1][0], gA + 64, K);
    asm volatile("s_waitcnt vmcnt(4)" ::: "memory");
  } else {
    asm volatile("s_waitcnt vmcnt(0)" ::: "memory");
  }
  SBAR0();
  __builtin_amdgcn_s_barrier();
  SBAR0();

  for (int kt = 0; kt < nk; ++kt) {
    const int c = kt & 1;
    bf16x8 af[4][2], b01[2][2], b23[2][2];

    // ---------- Phase 1: read af + b01; stage B(kt+1) -> c^1 ----------
#pragma unroll
    for (int mf = 0; mf < 4; ++mf)
#pragma unroll
      for (int ks = 0; ks < 2; ++ks)
        af[mf][ks] = *(const bf16x8*)&sA[c][(wm + mf * 16 + r) * 64
                        + ((((ks << 2) + q) ^ r7) << 3)];
#pragma unroll
    for (int nf = 0; nf < 2; ++nf)
#pragma unroll
      for (int ks = 0; ks < 2; ++ks)
        b01[nf][ks] = *(const bf16x8*)&sB[c][(wn + nf * 16 + r) * 64
                        + ((((ks << 2) + q) ^ r7) << 3)];
    if (kt + 1 < nk) stage(&sB[c ^ 1][0], gB + (size_t)(kt + 1) * 64, K);
    SBAR0();
    __builtin_amdgcn_s_barrier();
    SBAR0();
    __builtin_amdgcn_s_setprio(1);
#pragma unroll
    for (int mf = 0; mf < 4; ++mf)
#pragma unroll
      for (int nf = 0; nf < 2; ++nf)
#pragma unroll
        for (int ks = 0; ks < 2; ++ks)
          acc[mf][nf] = __builtin_amdgcn_mfma_f32_16x16x32_bf16(
              af[mf][ks], b01[nf][ks], acc[mf][nf], 0, 0, 0);
    __builtin_amdgcn_s_setprio(0);
    SBAR0();

    // ---------- Phase 2: read b23; stage A(kt+2) -> c; counted vmcnt ----------
#pragma unroll
    for (int nf = 0; nf < 2; ++nf)
#pragma unroll
      for (int ks = 0; ks < 2; ++ks)
        b23[nf][ks] = *(const bf16x8*)&sB[c][(wn + (nf + 2) * 16 + r) * 64
                        + ((((ks << 2) + q) ^ r7) << 3)];
    if (kt + 2 < nk) stage(&sA[c][0], gA + (size_t)(kt + 2) * 64, K);
    if (kt + 2 < nk) asm volatile("s_waitcnt vmcnt(4)" ::: "memory");
    else             asm volatile("s_waitcnt vmcnt(0)" ::: "memory");
    SBAR0();
    __builtin_amdgcn_s_barrier();
    SBAR0();
    __builtin_amdgcn_s_setprio(1);
#pragma unroll
    for (int mf = 0; mf < 4; ++mf)
#pragma unroll
      for (int nf = 0; nf < 2; ++nf)
#pragma unroll
        for (int ks = 0; ks < 2; ++ks)
          acc[mf][nf + 2] = __builtin_amdgcn_mfma_f32_16x16x32_bf16(
              af[mf][ks], b23[nf][ks], acc[mf][nf + 2], 0, 0, 0);
    __builtin_amdgcn_s_setprio(0);
    SBAR0();
  }

  // ---- LDS-transpose epilogue (per-wave 64x64 region, stride 68 f32) ----
  __syncthreads();
  float* ep = (w < 2) ? ((float*)&sA[0][0] + w * 2048)
                      : ((float*)&sB[0][0] + (w - 2) * 2048);
  const int r2 = lane >> 2;
  const int ccol = ((lane & 3) ^ (r2 & 3)) * 16;
#pragma unroll
  for (int i = 0; i < 4; ++i) {
#pragma unroll
    for (int j = 0; j < 4; ++j)
#pragma unroll
      for (int t = 0; t < 4; ++t)
        ep[(q * 4 + t) * 68 + j * 16 + r] = acc[i][j][t];
    f32x4 w0 = *(const f32x4*)&ep[r2 * 68 + ccol + 0];
    f32x4 w1 = *(const f32x4*)&ep[r2 * 68 + ccol + 4];
    f32x4 w2 = *(const f32x4*)&ep[r2 * 68 + ccol + 8];
    f32x4 w3 = *(const f32x4*)&ep[r2 * 68 + ccol + 12];
    float vv[16];
#pragma unroll
    for (int k = 0; k < 4; ++k) {
      vv[k] = w0[k]; vv[4 + k] = w1[k]; vv[8 + k] = w2[k]; vv[12 + k] = w3[k];
    }
    const int row = m0 + wm + i * 16 + r2;
    const int colg = n0 + wn + ccol;
    const size_t idx = (size_t)row * N + colg;
    if (EPI == 3) {               // h = x + v -> bf16
      float ax[16];
      if (fl) {
        f32x4 a0 = *(const f32x4*)&addf[idx];
        f32x4 a1 = *(const f32x4*)&addf[idx + 4];
        f32x4 a2 = *(const f32x4*)&addf[idx + 8];
        f32x4 a3 = *(const f32x4*)&addf[idx + 12];
#pragma unroll
        for (int k = 0; k < 4; ++k) {
          ax[k] = a0[k]; ax[4 + k] = a1[k]; ax[8 + k] = a2[k]; ax[12 + k] = a3[k];
        }
      } else {
        u16x8 a0 = *(const u16x8*)&addbf[idx];
        u16x8 a1 = *(const u16x8*)&addbf[idx + 8];
#pragma unroll
        for (int k = 0; k < 8; ++k) { ax[k] = bf2f(a0[k]); ax[8 + k] = bf2f(a1[k]); }
      }
      u16x8 o0, o1;
#pragma unroll
      for (int k = 0; k < 8; ++k) {
        o0[k] = f2bf(vv[k] + ax[k]); o1[k] = f2bf(vv[8 + k] + ax[8 + k]);
      }
      *(u16x8*)&((u16*)Cp)[idx] = o0;
      *(u16x8*)&((u16*)Cp)[idx + 8] = o1;
    } else if (EPI == 4) {               // relu(v + b1) -> bf16
      u16x8 b0 = *(const u16x8*)&bias[colg];
      u16x8 b1 = *(const u16x8*)&bias[colg + 8];
      u16x8 o0, o1;
#pragma unroll
      for (int k = 0; k < 8; ++k) {
        o0[k] = f2bf(fmaxf(vv[k] + bf2f(b0[k]), 0.f));
        o1[k] = f2bf(fmaxf(vv[8 + k] + bf2f(b1[k]), 0.f));
      }
      *(u16x8*)&((u16*)Cp)[idx] = o0;
      *(u16x8*)&((u16*)Cp)[idx + 8] = o1;
    } else {                             // EPI 5: out = h(bf16) + v + b2
      u16x8 b0 = *(const u16x8*)&bias[colg];
      u16x8 b1 = *(const u16x8*)&bias[colg + 8];
      u16x8 a0 = *(const u16x8*)&addbf[idx];
      u16x8 a1 = *(const u16x8*)&addbf[idx + 8];
      float r0[8], r1[8];
#pragma unroll
      for (int k = 0; k < 8; ++k) {
        r0[k] = vv[k] + bf2f(b0[k]) + bf2f(a0[k]);
        r1[k] = vv[8 + k] + bf2f(b1[k]) + bf2f(a1[k]);
      }
      if (fl) {
        f32x4 f0, f1, f2, f3;
#pragma unroll
        for (int k = 0; k < 4; ++k) { f0[k] = r0[k]; f1[k] = r0[4 + k]; f2[k] = r1[k]; f3[k] = r1[4 + k]; }
        *(f32x4*)&((float*)Cp)[idx] = f0;
        *(f32x4*)&((float*)Cp)[idx + 4] = f1;
        *(f32x4*)&((float*)Cp)[idx + 8] = f2;
        *(f32x4*)&((float*)Cp)[idx + 12] = f3;
      } else {
        u16x8 o0, o1;
#pragma unroll
        for (int k = 0; k < 8; ++k) { o0[k] = f2bf(r0[k]); o1[k] = f2bf(r1[k]); }
        *(u16x8*)&((u16*)Cp)[idx] = o0;
        *(u16x8*)&((u16*)Cp)[idx + 8] = o1;
      }
    }
  }
}

// ---------------------------------------------------------------------------
// Single-K-tile GEMM for dt (M=8192, N=2048, K=64). Stage once -> one
// barrier -> 32 MFMA -> softplus epilogue. No pipeline (write-bound op).
// ---------------------------------------------------------------------------
template<int LNBX>
__global__ __launch_bounds__(256, 2)
void gemm_k64(const u16* __restrict__ A, const u16* __restrict__ Bc,
              const u16* __restrict__ Braw, const int* __restrict__ dtflag,
              const u16* __restrict__ bias, u16* __restrict__ Cp)
{
  __shared__ __align__(16) u16 sA[128 * 64];   // 16 KiB
  __shared__ __align__(16) u16 sB[128 * 64];   // 16 KiB
  const int fl = *dtflag;
  const u16* __restrict__ B = fl ? Bc : Braw;
  const int tid = threadIdx.x;
  const int lane = tid & 63;
  const int w = tid >> 6;
  const int b = blockIdx.x;
  const int wg = (b & 7) * ((int)gridDim.x >> 3) + (b >> 3);
  const int bx = wg & ((1 << LNBX) - 1);
  const int by = wg >> LNBX;
  const int m0 = by * 128;
  const int n0 = bx * 128;
  const int wm = (w & 1) * 64;
  const int wn = (w >> 1) * 64;
  const int r = lane & 15;
  const int q = lane >> 4;
  const int r7 = lane & 7;
  const int srow = lane >> 3;
  const int schunk = ((lane & 7) ^ (srow & 7)) << 3;

  auto stage = [&](u16* dst, const u16* gbase) {
#pragma unroll
    for (int j = 0; j < 4; ++j) {
      u16* l = dst + ((j * 4 + w) * 8) * 64;
      const u16* g = gbase + (size_t)((j * 4 + w) * 8 + srow) * 64 + schunk;
      g2l16(g, l);
    }
  };
  stage(&sA[0], A + (size_t)m0 * 64);
  stage(&sB[0], B + (size_t)n0 * 64);
  asm volatile("s_waitcnt vmcnt(0)" ::: "memory");
  SBAR0();
  __builtin_amdgcn_s_barrier();
  SBAR0();

  f32x4 acc[4][4];
#pragma unroll
  for (int i = 0; i < 4; ++i)
#pragma unroll
    for (int j = 0; j < 4; ++j)
#pragma unroll
      for (int t = 0; t < 4; ++t) acc[i][j][t] = 0.f;

  bf16x8 af[4][2], bfv[4][2];
#pragma unroll
  for (int mf = 0; mf < 4; ++mf)
#pragma unroll
    for (int ks = 0; ks < 2; ++ks)
      af[mf][ks] = *(const bf16x8*)&sA[(wm + mf * 16 + r) * 64
                      + ((((ks << 2) + q) ^ r7) << 3)];
#pragma unroll
  for (int nf = 0; nf < 4; ++nf)
#pragma unroll
    for (int ks = 0; ks < 2; ++ks)
      bfv[nf][ks] = *(const bf16x8*)&sB[(wn + nf * 16 + r) * 64
                      + ((((ks << 2) + q) ^ r7) << 3)];
#pragma unroll
  for (int mf = 0; mf < 4; ++mf)
#pragma unroll
    for (int nf = 0; nf < 4; ++nf)
#pragma unroll
      for (int ks = 0; ks < 2; ++ks)
        acc[mf][nf] = __builtin_amdgcn_mfma_f32_16x16x32_bf16(
            af[mf][ks], bfv[nf][ks], acc[mf][nf], 0, 0, 0);

  // ---- LDS-transpose epilogue + softplus ----
  __syncthreads();
  float* ep = (w < 2) ? ((float*)&sA[0] + w * 2048)
                      : ((float*)&sB[0] + (w - 2) * 2048);
  const int r2 = lane >> 2;
  const int ccol = ((lane & 3) ^ (r2 & 3)) * 16;
#pragma unroll
  for (int i = 0; i < 4; ++i) {
#pragma unroll
    for (int j = 0; j < 4; ++j)
#pragma unroll
      for (int t = 0; t < 4; ++t)
        ep[(q * 4 + t) * 68 + j * 16 + r] = acc[i][j][t];
    f32x4 w0 = *(const f32x4*)&ep[r2 * 68 + ccol + 0];
    f32x4 w1 = *(const f32x4*)&ep[r2 * 68 + ccol + 4];
    f32x4 w2 = *(const f32x4*)&ep[r2 * 68 + ccol + 8];
    f32x4 w3 = *(const f32x4*)&ep[r2 * 68 + ccol + 12];
    float vv[16];
#pragma unroll
    for (int k = 0; k < 4; ++k) {
      vv[k] = w0[k]; vv[4 + k] = w1[k]; vv[8 + k] = w2[k]; vv[12 + k] = w3[k];
    }
    const int row = m0 + wm + i * 16 + r2;
    const int colg = n0 + wn + ccol;
    const size_t idx = (size_t)row * DI + colg;
    u16x8 b0 = *(const u16x8*)&bias[colg];
    u16x8 b1 = *(const u16x8*)&bias[colg + 8];
    u16x8 o0, o1;
#pragma unroll
    for (int k = 0; k < 8; ++k) {
      float v0 = vv[k] + bf2f(b0[k]);
      float v1 = vv[8 + k] + bf2f(b1[k]);
      v0 = (v0 > 15.f) ? v0 : __logf(1.f + __expf(v0));
      v1 = (v1 > 15.f) ? v1 : __logf(1.f + __expf(v1));
      o0[k] = f2bf(v0); o1[k] = f2bf(v1);
    }
    *(u16x8*)&Cp[idx] = o0;
    *(u16x8*)&Cp[idx + 8] = o1;
  }
}

// ---------------------------------------------------------------------------
// x_proj split-K: part[z] = u[:, z*256:(z+1)*256] @ w_xproj[:, same]^T
// ---------------------------------------------------------------------------
__global__ __launch_bounds__(256, 2)
void xproj_splitk(const u16* __restrict__ A, const u16* __restrict__ Bc,
                  const u16* __restrict__ Braw, const int* __restrict__ dtflag,
                  float* __restrict__ part)
{
  __shared__ __align__(16) u16 sA[2][128 * 32];
  __shared__ __align__(16) u16 sB[2][128 * 32];
  const int fl = *dtflag;
  const u16* __restrict__ B = fl ? Bc : Braw;
  const int tid = threadIdx.x;
  const int kz = blockIdx.x;           // 0..7
  const int m0 = blockIdx.y * 128;
  const int kbase = kz * 256;
  const int lane = tid & 63;
  const int wv = tid >> 6;
  const int wm = (wv & 1) * 64;
  const int wn = (wv >> 1) * 64;
  const int r = lane & 15;
  const int q = lane >> 4;
  const int rsw = (r >> 1) & 3;
  const int pr = lane >> 2;
  const int kc = (lane & 3) ^ ((pr >> 1) & 3);
  const int pk = kc * 8;

  u16* lA0[2] = { &sA[0][(wv * 2 + 0) * 512], &sA[1][(wv * 2 + 0) * 512] };
  u16* lA1[2] = { &sA[0][(wv * 2 + 1) * 512], &sA[1][(wv * 2 + 1) * 512] };
  u16* lB0[2] = { &sB[0][(wv * 2 + 0) * 512], &sB[1][(wv * 2 + 0) * 512] };
  u16* lB1[2] = { &sB[0][(wv * 2 + 1) * 512], &sB[1][(wv * 2 + 1) * 512] };
  int br0 = wv * 32 + pr;      if (br0 > 67) br0 = 67;   // junk cols unused
  int br1 = wv * 32 + 16 + pr; if (br1 > 67) br1 = 67;
  const u16* gA0 = A + (size_t)(m0 + wv * 32 + pr) * DI + kbase + pk;
  const u16* gA1 = gA0 + (size_t)16 * DI;
  const u16* gB0 = B + (size_t)br0 * DI + kbase + pk;
  const u16* gB1 = B + (size_t)br1 * DI + kbase + pk;

  f32x4 acc[4][4];
#pragma unroll
  for (int i = 0; i < 4; ++i)
#pragma unroll
    for (int j = 0; j < 4; ++j)
#pragma unroll
      for (int t = 0; t < 4; ++t) acc[i][j][t] = 0.f;

  g2l16(gA0, lA0[0]); g2l16(gA1, lA1[0]);
  g2l16(gB0, lB0[0]); g2l16(gB1, lB1[0]);

  for (int kt = 0; kt < 8; ++kt) {
    const int cur = kt & 1;
    __syncthreads();
    bf16x8 af[4], bfr[4];
#pragma unroll
    for (int i = 0; i < 4; ++i)
      af[i] = *reinterpret_cast<const bf16x8*>(
          &sA[cur][(wm + i * 16 + r) * 32 + (q ^ rsw) * 8]);
#pragma unroll
    for (int j = 0; j < 4; ++j)
      bfr[j] = *reinterpret_cast<const bf16x8*>(
          &sB[cur][(wn + j * 16 + r) * 32 + (q ^ rsw) * 8]);
    if (kt + 1 < 8) {
      gA0 += 32; gA1 += 32; gB0 += 32; gB1 += 32;
      g2l16(gA0, lA0[cur ^ 1]); g2l16(gA1, lA1[cur ^ 1]);
      g2l16(gB0, lB0[cur ^ 1]); g2l16(gB1, lB1[cur ^ 1]);
    }
#pragma unroll
    for (int i = 0; i < 4; ++i)
#pragma unroll
      for (int j = 0; j < 4; ++j)
        acc[i][j] = __builtin_amdgcn_mfma_f32_16x16x32_bf16(af[i], bfr[j], acc[i][j], 0, 0, 0);
  }

#pragma unroll
  for (int i = 0; i < 4; ++i)
#pragma unroll
    for (int j = 0; j < 4; ++j)
#pragma unroll
      for (int t = 0; t < 4; ++t) {
        const int row = m0 + wm + i * 16 + q * 4 + t;
        const int col = wn + j * 16 + r;
        if (col < NXP)
          part[((size_t)kz * NTOK + row) * NXP + col] = acc[i][j][t];
      }
}

// Reduce partials: cols 0..63 -> dtraw bf16 [NTOK,64]; 64..67 -> bc f32 [NTOK,4]
__global__ __launch_bounds__(256)
void xreduce_kernel(const float* __restrict__ part, u16* __restrict__ dtraw,
                    float* __restrict__ bc)
{
  const int i = blockIdx.x * 256 + threadIdx.x;
  if (i >= NTOK * NXP) return;
  const int row = i / NXP, col = i - row * NXP;
  float s = 0.f;
#pragma unroll
  for (int z = 0; z < 8; ++z) s += part[(size_t)z * NTOK * NXP + i];
  if (col < DTR) dtraw[(size_t)row * DTR + col] = f2bf(s);
  else           bc[row * 4 + (col - DTR)] = s;
}

// ---------------------------------------------------------------------------
// Depthwise causal conv + bias + SiLU, 16 tokens per block, window kept
// in registers (reads each xp row ~1.2x instead of 4x).
// ---------------------------------------------------------------------------
#define CTT 16
__global__ __launch_bounds__(256)
void conv_silu_tok(const u16* __restrict__ xp, const u16* __restrict__ cwT,
                   const u16* __restrict__ cb, u16* __restrict__ u)
{
  const int tok0 = blockIdx.x * CTT;        // global token of chunk start
  const int t0 = tok0 & (SEQ - 1);          // position within sequence
  const int d0 = threadIdx.x * 8;
  float w[4][8], cbv[8];
#pragma unroll
  for (int j = 0; j < 4; ++j) {
    u16x8 wv = *(const u16x8*)(cwT + j * DI + d0);
#pragma unroll
    for (int k = 0; k < 8; ++k) w[j][k] = bf2f(wv[k]);
  }
  u16x8 cbb = *(const u16x8*)(cb + d0);
#pragma unroll
  for (int k = 0; k < 8; ++k) cbv[k] = bf2f(cbb[k]);
  float xm0[8], xm1[8], xm2[8];             // x[t-3], x[t-2], x[t-1]
#pragma unroll
  for (int k = 0; k < 8; ++k) { xm0[k] = 0.f; xm1[k] = 0.f; xm2[k] = 0.f; }
  if (t0 != 0) {                            // chunk interior: all 3 priors valid
    u16x8 a = *(const u16x8*)(xp + (size_t)(tok0 - 3) * DI + d0);
    u16x8 bb = *(const u16x8*)(xp + (size_t)(tok0 - 2) * DI + d0);
    u16x8 c = *(const u16x8*)(xp + (size_t)(tok0 - 1) * DI + d0);
#pragma unroll
    for (int k = 0; k < 8; ++k) {
      xm0[k] = bf2f(a[k]); xm1[k] = bf2f(bb[k]); xm2[k] = bf2f(c[k]);
    }
  }
#pragma unroll
  for (int i = 0; i < CTT; ++i) {
    u16x8 xv = *(const u16x8*)(xp + (size_t)(tok0 + i) * DI + d0);
    float xc[8];
    u16x8 o;
#pragma unroll
    for (int k = 0; k < 8; ++k) {
      xc[k] = bf2f(xv[k]);
      const float a = cbv[k] + w[0][k] * xm0[k] + w[1][k] * xm1[k]
                    + w[2][k] * xm2[k] + w[3][k] * xc[k];
      const float sg = 1.f / (1.f + __expf(-a));
      o[k] = f2bf(a * sg);
    }
    *(u16x8*)(u + (size_t)(tok0 + i) * DI + d0) = o;
#pragma unroll
    for (int k = 0; k < 8; ++k) { xm0[k] = xm1[k]; xm1[k] = xm2[k]; xm2[k] = xc[k]; }
  }
}

// ---------------------------------------------------------------------------
// Chunked SSM scan (N=2 states), 4 channels per thread, CHUNK=32.
// ---------------------------------------------------------------------------
__global__ __launch_bounds__(256)
void scan_pass1(const u16* __restrict__ dtb, const u16* __restrict__ ub,
                const float* __restrict__ bc, const u16* __restrict__ a_log,
                float* __restrict__ S, float* __restrict__ hf0, float* __restrict__ hf1)
{
  const int g4 = blockIdx.x * 256 + threadIdx.x;   // NCHK*NCH/4
  const int chg = g4 & (NCH / 4 - 1);
  const int c = g4 >> 10;
  const int ch0 = chg * 4;
  const int b = ch0 >> 11;
  const int d0 = ch0 & (DI - 1);
  u16x8 av = *(const u16x8*)(a_log + d0 * 2);
  float A0[4], A1[4];
#pragma unroll
  for (int k = 0; k < 4; ++k) {
    A0[k] = -__expf(bf2f(av[2 * k]));
    A1[k] = -__expf(bf2f(av[2 * k + 1]));
  }
  float h0[4] = {0.f, 0.f, 0.f, 0.f}, h1[4] = {0.f, 0.f, 0.f, 0.f};
  float s[4] = {0.f, 0.f, 0.f, 0.f};
  const int row0 = b * SEQ + c * CHUNK;
  for (int i = 0; i < CHUNK; ++i) {
    const size_t row = row0 + i;
    u16x4 dtv = *(const u16x4*)(dtb + row * DI + d0);
    u16x4 uv  = *(const u16x4*)(ub + row * DI + d0);
    f32x2 Bv = *(const f32x2*)(bc + row * 4);
#pragma unroll
    for (int k = 0; k < 4; ++k) {
      const float dt = bf2f(dtv[k]);
      const float dtu = dt * bf2f(uv[k]);
      h0[k] = __expf(A0[k] * dt) * h0[k] + dtu * Bv[0];
      h1[k] = __expf(A1[k] * dt) * h1[k] + dtu * Bv[1];
      s[k] += dt;
    }
  }
  const size_t g0 = (size_t)c * NCH + ch0;
  *(f32x4*)(S + g0)   = f32x4{s[0], s[1], s[2], s[3]};
  *(f32x4*)(hf0 + g0) = f32x4{h0[0], h0[1], h0[2], h0[3]};
  *(f32x4*)(hf1 + g0) = f32x4{h1[0], h1[1], h1[2], h1[3]};
}

__global__ __launch_bounds__(256)
void scan_pass2(const float* __restrict__ S, const float* __restrict__ hf0,
                const float* __restrict__ hf1, const u16* __restrict__ a_log,
                float* __restrict__ hi0, float* __restrict__ hi1)
{
  const int ch = blockIdx.x * 256 + threadIdx.x;  // NCH
  const int d = ch & (DI - 1);
  const float A0 = -__expf(bf2f(a_log[d * 2 + 0]));
  const float A1 = -__expf(bf2f(a_log[d * 2 + 1]));
  float h0 = 0.f, h1 = 0.f;
  size_t g = ch;
  float sv = S[g], f0 = hf0[g], f1 = hf1[g];
  for (int c = 0; c < NCHK; ++c) {
    float svn = 0.f, f0n = 0.f, f1n = 0.f;
    if (c + 1 < NCHK) {
      const size_t gn = g + NCH;
      svn = S[gn]; f0n = hf0[gn]; f1n = hf1[gn];
    }
    hi0[g] = h0; hi1[g] = h1;
    h0 = __expf(A0 * sv) * h0 + f0;
    h1 = __expf(A1 * sv) * h1 + f1;
    sv = svn; f0 = f0n; f1 = f1n;
    g += NCH;
  }
}

__global__ __launch_bounds__(256)
void scan_pass3(const u16* __restrict__ dtb, const u16* __restrict__ ub,
                const float* __restrict__ bc, const u16* __restrict__ zbuf,
                const u16* __restrict__ a_log, const u16* __restrict__ d_skip,
                const float* __restrict__ hi0, const float* __restrict__ hi1,
                u16* __restrict__ yb)
{
  const int g4 = blockIdx.x * 256 + threadIdx.x;
  const int chg = g4 & (NCH / 4 - 1);
  const int c = g4 >> 10;
  const int ch0 = chg * 4;
  const int b = ch0 >> 11;
  const int d0 = ch0 & (DI - 1);
  u16x8 av = *(const u16x8*)(a_log + d0 * 2);
  u16x4 dkv = *(const u16x4*)(d_skip + d0);
  float A0[4], A1[4], dsk[4];
#pragma unroll
  for (int k = 0; k < 4; ++k) {
    A0[k] = -__expf(bf2f(av[2 * k]));
    A1[k] = -__expf(bf2f(av[2 * k + 1]));
    dsk[k] = bf2f(dkv[k]);
  }
  const size_t g0 = (size_t)c * NCH + ch0;
  f32x4 h0v = *(const f32x4*)(hi0 + g0);
  f32x4 h1v = *(const f32x4*)(hi1 + g0);
  float h0[4], h1[4];
#pragma unroll
  for (int k = 0; k < 4; ++k) { h0[k] = h0v[k]; h1[k] = h1v[k]; }
  const int row0 = b * SEQ + c * CHUNK;
  for (int i = 0; i < CHUNK; ++i) {
    const size_t row = row0 + i;
    u16x4 dtv = *(const u16x4*)(dtb + row * DI + d0);
    u16x4 uv  = *(const u16x4*)(ub + row * DI + d0);
    u16x4 zv  = *(const u16x4*)(zbuf + row * DI + d0);
    f32x4 bcv = *(const f32x4*)(bc + row * 4);
    u16x4 o;
#pragma unroll
    for (int k = 0; k < 4; ++k) {
      const float dt = bf2f(dtv[k]);
      const float uu = bf2f(uv[k]);
      const float dtu = dt * uu;
      h0[k] = __expf(A0[k] * dt) * h0[k] + dtu * bcv[0];
      h1[k] = __expf(A1[k] * dt) * h1[k] + dtu * bcv[1];
      const float y = h0[k] * bcv[2] + h1[k] * bcv[3];
      const float z = bf2f(zv[k]);
      const float sz = z / (1.f + __expf(-z));
      o[k] = f2bf((y + dsk[k] * uu) * sz);
    }
    *(u16x4*)(yb + row * DI + d0) = o;    // in-place over dtb: ok
  }
}

// ---------------------------------------------------------------------------
extern "C" void kernel_launch(void* const* d_in, const int* in_sizes, int n_in,
                              void* d_out, int out_size, void* d_ws, size_t ws_size,
                              hipStream_t stream)
{
  const void* x       = d_in[0];
  const void* w_in    = d_in[1];
  const void* conv_w  = d_in[2];
  const void* conv_b  = d_in[3];
  const void* w_xproj = d_in[4];
  const void* w_dt    = d_in[5];
  const void* b_dt    = d_in[6];
  const void* a_log   = d_in[7];
  const void* d_skip  = d_in[8];
  const void* w_out   = d_in[9];
  const void* ln1_g   = d_in[10];
  const void* ln1_b   = d_in[11];
  const void* ln2_g   = d_in[12];
  const void* ln2_b   = d_in[13];
  const void* ffn_w1  = d_in[14];
  const void* ffn_b1  = d_in[15];
  const void* ffn_w2  = d_in[16];
  const void* ffn_b2  = d_in[17];
  char* ws = (char*)d_ws;

  // ---- workspace layout (high-water ~127 MB) ----
  const size_t o_flag  = 0;
  const size_t o_small = 256;
  const size_t o_cwout = o_small + 65536;
  const size_t o_cff1  = o_cwout + (size_t)DM * DI * 2;
  const size_t o_cff2  = o_cff1  + (size_t)DM * DM * 2;
  const size_t o_cxp   = o_cff2  + (size_t)DM * DM * 2;
  const size_t o_cwdt  = o_cxp   + (size_t)NXP * DI * 2;
  const size_t o_xn    = 9437184;                         // 16 MiB region
  const size_t o_xp    = o_xn + (size_t)NTOK * DM * 2;    // 32 MiB
  const size_t o_z     = o_xp + (size_t)NTOK * DI * 2;    // 32 MiB
  const size_t o_u     = o_z  + (size_t)NTOK * DI * 2;    // 32 MiB
  const size_t o_bc    = o_u  + (size_t)NTOK * DI * 2;    // 128 KiB
  const size_t SCN = (size_t)NCHK * NCH * 4;              // 2 MiB each
  const size_t o_S   = o_xn + 0 * SCN;
  const size_t o_hf0 = o_xn + 1 * SCN;
  const size_t o_hf1 = o_xn + 2 * SCN;
  const size_t o_hi0 = o_xn + 3 * SCN;
  const size_t o_hi1 = o_xn + 4 * SCN;

  int*   flagp   = (int*)(ws + o_flag);
  u16*   csmall  = (u16*)(ws + o_small);
  u16*   c_cwT   = csmall +     0;       // transposed conv weights [4][DI]
  u16*   c_convb = csmall +  8192;
  u16*   c_bdt   = csmall + 10240;
  u16*   c_alog  = csmall + 12288;
  u16*   c_dskip = csmall + 16384;
  u16*   c_ln1g  = csmall + 18432;
  u16*   c_ln1b  = csmall + 19456;
  u16*   c_ln2g  = csmall + 20480;
  u16*   c_ln2b  = csmall + 21504;
  u16*   c_fb1   = csmall + 22528;
  u16*   c_fb2   = csmall + 23552;
  u16*   c_wout  = (u16*)(ws + o_cwout);
  u16*   c_ff1   = (u16*)(ws + o_cff1);
  u16*   c_ff2   = (u16*)(ws + o_cff2);
  u16*   c_xproj = (u16*)(ws + o_cxp);
  u16*   c_wdt   = (u16*)(ws + o_cwdt);
  u16*   c_win   = (u16*)(ws + o_u);     // overlays u (dead until conv)
  u16*   xn      = (u16*)(ws + o_xn);
  u16*   xp      = (u16*)(ws + o_xp);
  u16*   zb      = (u16*)(ws + o_z);
  u16*   u       = (u16*)(ws + o_u);
  float* part    = (float*)(ws + o_xp);  // overlays xp (dead after conv)
  u16*   dtraw   = (u16*)(ws + o_xn);    // overlays xn (dead after in_proj)
  u16*   dtb     = xp;                   // overlays part (dead after reduce)
  u16*   yb      = xp;
  float* bc      = (float*)(ws + o_bc);
  float* S       = (float*)(ws + o_S);
  float* hf0     = (float*)(ws + o_hf0);
  float* hf1     = (float*)(ws + o_hf1);
  float* hi0     = (float*)(ws + o_hi0);
  float* hi1     = (float*)(ws + o_hi1);
  u16*   hb      = (u16*)(ws + o_z);     // h as bf16, overlays z (dead after pass3)
  u16*   hn      = (u16*)(ws + o_xn);    // overlays scan arrays (dead)
  u16*   f1      = (u16*)(ws + o_u);     // overlays u (dead)

  const dim3 blk(256);

  // 0) detect dtype; all param conversion in ONE launch
  detect_kernel<<<1, blk, 0, stream>>>((const u16*)x, flagp);
  convert_all<<<NBB + 96, blk, 0, stream>>>(
      (const float*)w_in, (const float*)w_xproj, (const float*)w_dt,
      (const float*)w_out, (const float*)ffn_w1, (const float*)ffn_w2,
      c_win, c_xproj, c_wdt, c_wout, c_ff1, c_ff2,
      conv_w, conv_b, b_dt, a_log, d_skip,
      ln1_g, ln1_b, ln2_g, ln2_b, ffn_b1, ffn_b2,
      csmall, flagp);

  // 1) LN1(x) -> xn
  ln_kernel<0><<<NTOK / 2, blk, 0, stream>>>(x, c_ln1g, c_ln1b, xn, flagp);
  // 2) fused in_proj: [xp | z] = xn @ w_in^T  (256x256 2-phase, no hand-drains)
  gemm256_kernel<6, 4><<<512, dim3(512), 0, stream>>>(
      xn, c_win, (const u16*)w_in, NTOK, 2 * DI, DM, flagp, xp, zb);
  // 3) u = silu(conv(xp) + conv_b)   (16 tokens/block, register window)
  conv_silu_tok<<<NTOK / CTT, blk, 0, stream>>>(xp, c_cwT, c_convb, u);
  // 4) x_proj split-K (partials) + reduce -> dtraw (bf16), bc (f32)
  xproj_splitk<<<dim3(8, 64), blk, 0, stream>>>(u, c_xproj, (const u16*)w_xproj,
                                                flagp, part);
  xreduce_kernel<<<(NTOK * NXP + 255) / 256, blk, 0, stream>>>(part, dtraw, bc);
  // 5) dt = softplus(dtraw @ w_dt^T + b_dt)   (single-K-tile kernel)
  gemm_k64<4><<<1024, blk, 0, stream>>>(dtraw, c_wdt, (const u16*)w_dt,
                                        flagp, c_bdt, dtb);
  // 6) chunked scan -> yb = (y + d_skip*u) * silu(z)
  scan_pass1<<<NCHK * NCH / 4 / 256, blk, 0, stream>>>(dtb, u, bc, c_alog, S, hf0, hf1);
  scan_pass2<<<NCH / 256, blk, 0, stream>>>(S, hf0, hf1, c_alog, hi0, hi1);
  scan_pass3<<<NCHK * NCH / 4 / 256, blk, 0, stream>>>(dtb, u, bc, zb, c_alog, c_dskip,
                                                       hi0, hi1, yb);
  // 7) h = bf16(x + yb @ w_out^T)   (dp, grid 64*8=512, nk=32)
  gemm_dp<3, 3><<<512, blk, 0, stream>>>(yb, c_wout, (const u16*)w_out,
                                         NTOK, DM, DI,
                                         nullptr, (const u16*)x, (const float*)x,
                                         flagp, hb, nullptr);
  // 8) LN2(h) -> hn   (bf16 input)
  ln_kernel<1><<<NTOK / 2, blk, 0, stream>>>(hb, c_ln2g, c_ln2b, hn, flagp);
  // 9) f1 = relu(hn @ ffn_w1^T + b1)   (dp, nk=16)
  gemm_dp<4, 3><<<512, blk, 0, stream>>>(hn, c_ff1, (const u16*)ffn_w1,
                                         NTOK, DM, DM,
                                         c_fb1, nullptr, nullptr, flagp, f1, nullptr);
  // 10) out = h + f1 @ ffn_w2^T + b2   (dp, nk=16)
  gemm_dp<5, 3><<<512, blk, 0, stream>>>(f1, c_ff2, (const u16*)ffn_w2,
                                         NTOK, DM, DM,
                                         c_fb2, hb, nullptr, flagp, d_out, nullptr);
}